// Round 15
// baseline (293.154 us; speedup 1.0000x reference)
//
#include <hip/hip_runtime.h>
#include <stdint.h>

typedef unsigned int uint;
typedef unsigned short ushort;
typedef __attribute__((ext_vector_type(8))) short short8;
typedef __attribute__((ext_vector_type(4))) float f32x4;

__device__ __forceinline__ uint f2bf(float f) {
  uint u = __float_as_uint(f);
  return (u + 0x7fffu + ((u >> 16) & 1u)) >> 16;
}
__device__ __forceinline__ float bf2f(uint us) {
  return __uint_as_float(us << 16);
}
__device__ __forceinline__ uint cvtpk_bf16(float lo, float hi) {
  uint r;
  asm("v_cvt_pk_bf16_f32 %0, %1, %2" : "=v"(r) : "v"(lo), "v"(hi));
  return r;
}
__device__ __forceinline__ int lt_count(unsigned long long m) {
  return (int)__builtin_amdgcn_mbcnt_hi((uint)(m >> 32),
             __builtin_amdgcn_mbcnt_lo((uint)m, 0u));
}

// ---------------- fused: weight preprocessing + x transpose ----------------
// blocks 0..255: transpose_x (bf16 xT + fp32 xT + sqnorm).
// blocks 256..4927: prep_weights (wp1 + wpack), g = (blk-256)*256+tid.
__global__ __launch_bounds__(256) void prep_transpose(
    const float* __restrict__ w1, const float* __restrict__ w2,
    ushort* __restrict__ wp1, ushort* __restrict__ wpack,
    const float* __restrict__ x, uint* __restrict__ xtu,
    float* __restrict__ xtf, float* __restrict__ sqf) {
  __shared__ float t[64][65];
  int tid = threadIdx.x;
  if (blockIdx.x >= 256) {
    int g = (blockIdx.x - 256) * 256 + tid;
    if (g < 196608) {
      int chunk = g >> 9;            // (t*2+ks)*16 + ctile
      int r = g & 511;
      int lane = r >> 3, j = r & 7;
      int tks = chunk >> 4;
      int ctile = chunk & 15;
      int tt0 = tks >> 1, ks = tks & 1;
      int c = ctile * 16 + (lane & 15);
      int d = ks * 32 + ((lane >> 4) << 3) + j;
      float val;
      if (tt0 < 11) {
        val = w1[c * 1408 + (64 + d) * 11 + tt0];
      } else {
        float s = 0.f;
        for (int tt = 0; tt < 11; ++tt)
          s += w1[c * 1408 + d * 11 + tt] - w1[c * 1408 + (64 + d) * 11 + tt];
        val = s;
      }
      wp1[g] = (ushort)f2bf(val);
    } else {
      int gp = g - 196608;            // < 999424 = 61*16384
      int chunk = gp >> 9;            // (kb*2+ks)*16 + ctile
      int r = gp & 511;
      int lane = r >> 3, j = r & 7;
      int kb = chunk >> 5;
      int rem = chunk & 31;
      int ks = rem >> 4, ctile = rem & 15;
      int c = ctile * 16 + (lane & 15);
      int k = kb * 64 + ks * 32 + ((lane >> 4) << 3) + j;
      float val;
      if (k < 64) {
        int d = k;
        float s = 0.f;
        for (int jn = 0; jn < 20; ++jn)
          s += w2[c * 5120 + d * 40 + jn] - w2[c * 5120 + (64 + d) * 40 + jn];
        val = s;
      } else if (k < 1344) {
        int q = k - 64; int jn = q >> 6, d = q & 63;
        val = w2[c * 5120 + (64 + d) * 40 + jn];
      } else {
        int q = k - 1344; int ci = q / 20, jj = q - ci * 20;
        val = w2[c * 5120 + ci * 40 + 20 + jj];
      }
      wpack[gp] = (ushort)f2bf(val);
    }
    return;
  }
  // ---- transpose part (manual f2bf kept: feeds kNN ranking) ----
  int blk = blockIdx.x;            // 256 = 8 b x 32 n-tiles
  int b = blk >> 5, n0 = (blk & 31) << 6;
  const float* xb = x + b * 131072;
  #pragma unroll
  for (int it = 0; it < 16; ++it) {
    int d = (it << 2) + (tid >> 6);
    int n = tid & 63;
    t[d][n] = xb[d * 2048 + n0 + n];
  }
  __syncthreads();
  #pragma unroll
  for (int it = 0; it < 8; ++it) {
    int n = (it << 3) + (tid >> 5);
    int dp = tid & 31;
    float f0 = t[2 * dp][n], f1 = t[2 * dp + 1][n];
    uint v = f2bf(f0) | (f2bf(f1) << 16);
    size_t col = (size_t)(b * 2048 + n0 + n);
    xtu[col * 32 + dp] = v;
    float2 fv; fv.x = f0; fv.y = f1;
    *(float2*)&xtf[(col << 6) + 2 * dp] = fv;
    float s = f0 * f0 + f1 * f1;
    #pragma unroll
    for (int off = 16; off > 0; off >>= 1) s += __shfl_xor(s, off);
    if (dp == 0) sqf[col] = s;
  }
}

// ---------------- kNN v11: threshold + compact + rank.
// Self-exclusion folded into the dist write (no cross-lane hazard).
// Phase-1 reads 4 x uint4 per lane (lane owns 4 consecutive cols) — output
// is partition-invariant: top-32 \subseteq survivors for ANY lane partition
// (any key > T has >=32 smaller keys), ranks value-based on unique keys
// -> bit-identical cbuf. Dist rows padded to 1040 (2-way = free). ----------------
__global__ __launch_bounds__(1024) void knn_kernel(
    const ushort* __restrict__ xbf_t, const float* __restrict__ sqf,
    int* __restrict__ cbuf) {
  __shared__ uint dist[16][1040];   // 66560 B (padded rows)
  __shared__ uint surv[16][132];    // 8448 B (128 max survivors + pad)
  int tid = threadIdx.x;
  int wv = tid >> 6, lane = tid & 63;
  int grp = blockIdx.x >> 1;
  int half = blockIdx.x & 1;
  int cbase = half << 10;
  int row0 = grp << 4;
  int b = row0 >> 11, n0 = row0 & 2047;
  const ushort* xt = xbf_t + ((size_t)b << 17);
  const float* sqb = sqf + (b << 11);
  int m = lane & 15, quad = lane >> 4;
  short8 afr0 = *(const short8*)(xt + ((size_t)(n0 + m) << 6) + quad * 8);
  short8 afr1 = *(const short8*)(xt + ((size_t)(n0 + m) << 6) + 32 + quad * 8);
  for (int t = 0; t < 4; ++t) {
    int lcol = (((wv << 2) + t) << 4) + m;
    int col = cbase + lcol;
    short8 bfr0 = *(const short8*)(xt + ((size_t)col << 6) + quad * 8);
    short8 bfr1 = *(const short8*)(xt + ((size_t)col << 6) + 32 + quad * 8);
    f32x4 c = {};
    c = __builtin_amdgcn_mfma_f32_16x16x32_bf16(afr0, bfr0, c, 0, 0, 0);
    c = __builtin_amdgcn_mfma_f32_16x16x32_bf16(afr1, bfr1, c, 0, 0, 0);
    float sq = sqb[col];
    #pragma unroll
    for (int r = 0; r < 4; ++r) {
      int drow = quad * 4 + r;
      float f = sq - 2.f * c[r];
      uint u = __float_as_uint(f);
      uint srt = u ^ ((uint)((int)u >> 31) | 0x80000000u);
      uint keyv = (srt & 0xFFFFF800u) | (uint)col;
      if (col == n0 + drow) keyv = 0xFFFFFFFFu;   // self-exclusion inline
      dist[drow][lcol] = keyv;
    }
  }
  __syncthreads();
  uint* dr = dist[wv];

  // phase 1: load this wave's 1024 keys, 4 consecutive per lane per chunk
  uint key[16];
  uint v0 = 0xFFFFFFFFu;
  #pragma unroll
  for (int l = 0; l < 4; ++l) {
    uint4 q = *(const uint4*)&dr[(l << 8) + (lane << 2)];
    key[4 * l + 0] = q.x; key[4 * l + 1] = q.y;
    key[4 * l + 2] = q.z; key[4 * l + 3] = q.w;
    uint m0 = q.x < q.y ? q.x : q.y;
    uint m1 = q.z < q.w ? q.z : q.w;
    m0 = m0 < m1 ? m0 : m1;
    v0 = v0 < m0 ? v0 : m0;
  }

  // phase 2: bitonic sort of the 64 lane-minima across lanes; T = element 31
  uint s = v0;
  #pragma unroll
  for (int k = 2; k <= 64; k <<= 1) {
    #pragma unroll
    for (int j = k >> 1; j > 0; j >>= 1) {
      uint o = (uint)__shfl_xor((int)s, j);
      bool up = ((lane & k) == 0);
      bool lower = ((lane & j) == 0);
      uint mn = s < o ? s : o;
      uint mx = s < o ? o : s;
      s = (lower == up) ? mn : mx;
    }
  }
  uint T = (uint)__shfl((int)s, 31);

  // phase 3: ballot-compact survivors (key <= T) into surv[wv]
  int base = 0;
  #pragma unroll
  for (int l = 0; l < 16; ++l) {
    uint v = key[l];
    bool f = (v <= T);
    unsigned long long mk = __ballot(f);
    if (f) {
      int pos = base + lt_count(mk);
      if (pos < 128) surv[wv][pos] = v;
    }
    base += __popcll(mk);
  }
  int S = base < 128 ? base : 128;
  if (lane < 4) surv[wv][S + lane] = 0xFFFFFFFFu;   // pad for b128 tail read

  // phase 4: exact rank of each survivor = count of strictly-smaller survivors
  int outb = (row0 + wv) * 64 + (half << 5);
  uint k0 = (lane < S) ? surv[wv][lane] : 0xFFFFFFFFu;
  int r0 = 0;
  if (S > 64) {
    uint k1 = (lane + 64 < S) ? surv[wv][lane + 64] : 0xFFFFFFFFu;
    int r1 = 0;
    for (int i = 0; i < S; i += 4) {
      uint4 q = *(const uint4*)&surv[wv][i];   // broadcast read
      r0 += (q.x < k0) + (q.y < k0) + (q.z < k0) + (q.w < k0);
      r1 += (q.x < k1) + (q.y < k1) + (q.z < k1) + (q.w < k1);
    }
    if (lane + 64 < S && r1 < 32) cbuf[outb + r1] = (int)(k1 & 2047u);
  } else {
    for (int i = 0; i < S; i += 4) {
      uint4 q = *(const uint4*)&surv[wv][i];   // broadcast read
      r0 += (q.x < k0) + (q.y < k0) + (q.z < k0) + (q.w < k0);
    }
  }
  if (lane < S && r0 < 32) cbuf[outb + r0] = (int)(k0 & 2047u);
}

// ---------------- kNN merge: fp64 exact re-rank of 64 candidates/row ----------------
__global__ __launch_bounds__(256) void knn_merge(
    const float* __restrict__ xtf, const int* __restrict__ cbuf,
    int* __restrict__ idxout) {
  __shared__ double dkey[4][64];
  __shared__ int ccol[4][64];
  int tid = threadIdx.x;
  int wv = tid >> 6, lane = tid & 63;
  int row = (blockIdx.x << 2) + wv;
  int b = row >> 11, n = row & 2047;
  int ci = cbuf[row * 64 + lane];
  const float* xc = xtf + ((size_t)b << 17);
  const float4* xj4 = (const float4*)(xc + ((size_t)ci << 6));
  const float4* xi4 = (const float4*)(xc + ((size_t)n << 6));
  double dt = 0.0, s2 = 0.0;
  #pragma unroll 4
  for (int d4 = 0; d4 < 16; ++d4) {
    float4 vj = xj4[d4];
    float4 vi = xi4[d4];
    double a0 = (double)vj.x, a1 = (double)vj.y, a2 = (double)vj.z, a3 = (double)vj.w;
    s2 += a0 * a0 + a1 * a1 + a2 * a2 + a3 * a3;
    dt += (double)vi.x * a0 + (double)vi.y * a1 + (double)vi.z * a2 + (double)vi.w * a3;
  }
  dkey[wv][lane] = s2 - 2.0 * dt;
  ccol[wv][lane] = ci;
  __syncthreads();
  double kl = dkey[wv][lane];
  int rank = 0;
  for (int mm = 0; mm < 64; ++mm) {
    double km = dkey[wv][mm];
    int cm = ccol[wv][mm];
    if (km < kl || (km == kl && cm < ci)) ++rank;
  }
  if (rank < 20) idxout[row * 20 + rank] = ci;
}

// ---------------- conv1 as bf16 MFMA v5 + cvt_pk epilogue:
// 8-wave blocks (2 ctile passes/wave), chunk-major XOR-swizzled LDS.
// (v6 tap-split REVERTED: 6-waves/SIMD cap spilled acc — reg floor ~90.)
// Block: 16 points x 256 channels (8 waves; pass p: ctile = p*8+wave).
// LDS sl[s][chunk][p^chunk][8]: chunk = ks*4+quad (conflict-free, R6). ----------------
__global__ __launch_bounds__(512, 4) void conv1_mfma(
    const ushort* __restrict__ xbf_t, const int* __restrict__ idxbuf,
    const ushort* __restrict__ wp1, uint* __restrict__ hu,
    float* __restrict__ stats) {
  __shared__ ushort sl[21][8][16][8];   // 43008 B
  __shared__ int nidx[16][20];
  int tid = threadIdx.x;
  int p0 = blockIdx.x << 4;
  int b = p0 >> 11, n0 = p0 & 2047;
  const ushort* xt = xbf_t + ((size_t)b << 17);
  for (int v = tid; v < 320; v += 512) {
    int p = v / 20, j = v - p * 20;
    nidx[p][j] = idxbuf[(p0 + p) * 20 + j];
  }
  __syncthreads();
  for (int v = tid; v < 2688; v += 512) {
    int s = v >> 7;
    int r = v & 127;
    int p = r >> 3, i = r & 7;
    int col = (s == 0) ? (n0 + p) : nidx[p][s - 1];
    *(short8*)&sl[s][i][p ^ i][0] =
        *(const short8*)(xt + ((size_t)col << 6) + (i << 3));
  }
  __syncthreads();
  int lane = tid & 63, wave = tid >> 6;   // wave 0..7
  int m = lane & 15, quad = lane >> 4;
  #pragma unroll 1
  for (int pass = 0; pass < 2; ++pass) {
    int ctile = (pass << 3) + wave;
    int c = ctile * 16 + m;
    f32x4 acc[10] = {};
    f32x4 cacc = {};
    // ks-split: only 12 B-fragments (tb[11]+ub, 48 VGPRs) live at a time
    #pragma unroll 1
    for (int ks = 0; ks < 2; ++ks) {
      int cch = ks * 4 + quad;          // LDS chunk for this lane
      int ms = m ^ cch;                 // XOR-swizzled point slot
      short8 tb[11];
      #pragma unroll
      for (int t = 0; t < 11; ++t)
        tb[t] = *(const short8*)(wp1 + (((t * 2 + ks) * 16 + ctile) << 9) + lane * 8);
      short8 ub = *(const short8*)(wp1 + (((22 + ks) * 16 + ctile) << 9) + lane * 8);
      {
        short8 a = *(const short8*)&sl[0][cch][ms][0];
        cacc = __builtin_amdgcn_mfma_f32_16x16x32_bf16(a, ub, cacc, 0, 0, 0);
      }
      // slice-outer: read each slice once, accumulate into all valid ko = s-1-t
      #pragma unroll
      for (int s = 1; s <= 20; ++s) {
        short8 a = *(const short8*)&sl[s][cch][ms][0];
        #pragma unroll
        for (int t = 0; t < 11; ++t) {
          int ko = s - 1 - t;
          if (ko >= 0 && ko < 10)
            acc[ko] = __builtin_amdgcn_mfma_f32_16x16x32_bf16(a, tb[t], acc[ko], 0, 0, 0);
        }
      }
    }
    // epilogue: D col=lane&15 -> channel, row=quad*4+r -> point; fused stats
    float sacc = 0.f, ssacc = 0.f;
    #pragma unroll
    for (int r = 0; r < 4; ++r) {
      int p = (quad << 2) + r;
      int base5 = ((p0 + p) * 256 + c) * 5;
      float cc = cacc[r];
      #pragma unroll
      for (int q = 0; q < 5; ++q) {
        float f0 = acc[2 * q][r] + cc;
        float f1 = acc[2 * q + 1][r] + cc;
        sacc += f0 + f1;
        ssacc += f0 * f0 + f1 * f1;
        hu[base5 + q] = cvtpk_bf16(f0, f1);   // RNE pack, 1 instr vs ~7
      }
    }
    sacc += __shfl_xor(sacc, 16);  sacc += __shfl_xor(sacc, 32);
    ssacc += __shfl_xor(ssacc, 16); ssacc += __shfl_xor(ssacc, 32);
    if (quad == 0) {
      atomicAdd(&stats[c], sacc);
      atomicAdd(&stats[256 + c], ssacc);
    }
  }
}

// ---------------- conv2 as bf16 MFMA GEMM v11: M=64 x N=128 tiles
// (grid 512 = 2 blocks/CU, no tail). BN1 coefs in-kernel. Epilogue writes
// yraw TRANSPOSED (b,c,n) as one float4 per mt (acc r-values are consecutive
// n) — same 64B-per-16-lane coalescing, 4x fewer stores, and out_kernel
// becomes pure streaming. R8 conflict-free XOR swizzle kept. ----------------
__global__ __launch_bounds__(512, 4) void conv2_mfma(
    const ushort* __restrict__ xbf_t, const int* __restrict__ idxbuf,
    const uint* __restrict__ hu, const float* __restrict__ stats1,
    const float* __restrict__ g1, const float* __restrict__ be1,
    const ushort* __restrict__ wpack, float* __restrict__ yrawT,
    float* __restrict__ stats) {
  __shared__ ushort As[2][4][64][64];   // 65536 B (swizzled)
  __shared__ int nidx[64][20];          // 5120 B
  __shared__ float cfA[257], cfB[257];  // 2056 B -> total 72712 B
  int tid = threadIdx.x;
  int nblk = blockIdx.x & 1;            // N-half: cols nblk*128..+127
  int p0 = (blockIdx.x >> 1) << 6;      // 64 points per block
  int b = p0 >> 11, n0 = p0 & 2047;
  const ushort* xt = xbf_t + ((size_t)b << 17);

  if (tid < 256) {
    float mm = stats1[tid] * (1.f / 163840.f);
    float var = stats1[256 + tid] * (1.f / 163840.f) - mm * mm;
    float a = g1[tid] * rsqrtf(var + 1e-5f);
    cfA[tid] = a;
    cfB[tid] = be1[tid] - mm * a;
    if (tid == 0) { cfA[256] = 0.f; cfB[256] = 0.f; }
  }
  for (int v = tid; v < 1280; v += 512) {
    int p = v / 20, j = v - p * 20;
    nidx[p][j] = idxbuf[(p0 + p) * 20 + j];
  }
  __syncthreads();

  int pp = tid >> 3;                 // point 0..63
  int t7 = tid & 7;
  int off = t7 << 3;                 // logical 8-col chunk within 64
  int wroff = ((t7 ^ (pp & 7)) << 3);  // swizzled write offset (ushorts)

  auto build = [&](int phase, int buf) {
    int kb0 = phase << 2;
    short8 xv[4];
    uint4 hv[4];
    #pragma unroll
    for (int kc = 0; kc < 4; ++kc) {
      int kb = kb0 + kc;
      if (kb >= 61) continue;
      if (kb < 21) {
        int col = (kb == 0) ? (n0 + pp) : nidx[pp][kb - 1];
        xv[kc] = *(const short8*)(xt + ((size_t)col << 6) + off);
      } else {
        int q0 = (kb - 21) * 64 + off;
        hv[kc] = *(const uint4*)(hu + (size_t)(p0 + pp) * 1280 + (q0 >> 1));
      }
    }
    #pragma unroll
    for (int kc = 0; kc < 4; ++kc) {
      int kb = kb0 + kc;
      if (kb >= 61) continue;
      if (kb < 21) {
        *(short8*)&As[buf][kc][pp][wroff] = xv[kc];
      } else {
        int q0 = (kb - 21) * 64 + off;
        uint4 hvv = hv[kc];
        float f[8];
        f[0] = bf2f(hvv.x & 0xffffu); f[1] = bf2f(hvv.x >> 16);
        f[2] = bf2f(hvv.y & 0xffffu); f[3] = bf2f(hvv.y >> 16);
        f[4] = bf2f(hvv.z & 0xffffu); f[5] = bf2f(hvv.z >> 16);
        f[6] = bf2f(hvv.w & 0xffffu); f[7] = bf2f(hvv.w >> 16);
        int ch0 = q0 / 10;
        int rem = q0 - ch0 * 10;      // one magic-div per 8 elements
        float a0 = cfA[ch0], b0 = cfB[ch0];
        float a1 = cfA[ch0 + 1], b1 = cfB[ch0 + 1];
        uint4 wv4;
        uint rr[4];
        #pragma unroll
        for (int i = 0; i < 4; ++i) {
          bool hlo = (rem + 2 * i) >= 10;
          bool hhi = (rem + 2 * i + 1) >= 10;
          float vlo = f[2 * i]     * (hlo ? a1 : a0) + (hlo ? b1 : b0);
          float vhi = f[2 * i + 1] * (hhi ? a1 : a0) + (hhi ? b1 : b0);
          vlo = fmaxf(vlo, 0.01f * vlo);   // leaky: identical result, 2 ops
          vhi = fmaxf(vhi, 0.01f * vhi);
          rr[i] = cvtpk_bf16(vlo, vhi);    // RNE pack, 1 instr per pair
        }
        wv4.x = rr[0]; wv4.y = rr[1]; wv4.z = rr[2]; wv4.w = rr[3];
        *(uint4*)&As[buf][kc][pp][wroff] = wv4;
      }
    }
  };

  int lane = tid & 63, wave = tid >> 6;
  int m = lane & 15, quad = lane >> 4;
  // swizzled read chunk offsets (ushorts) for ks=0,1 — R8-verified pattern
  int rdoff0 = ((quad ^ (m & 7)) << 3);
  int rdoff1 = (((4 + quad) ^ (m & 7)) << 3);
  f32x4 acc[4] = {};

  build(0, 0);
  __syncthreads();
  for (int phase = 0; phase < 16; ++phase) {
    int buf = phase & 1;
    if (phase < 15) build(phase + 1, buf ^ 1);
    #pragma unroll
    for (int kc = 0; kc < 4; ++kc) {
      int kb = (phase << 2) + kc;
      if (kb >= 61) break;
      #pragma unroll
      for (int ks = 0; ks < 2; ++ks) {
        int rdoff = ks ? rdoff1 : rdoff0;
        short8 afr[4];
        #pragma unroll
        for (int mt = 0; mt < 4; ++mt)
          afr[mt] = *(const short8*)&As[buf][kc][mt * 16 + m][rdoff];
        const ushort* bp = wpack +
            (((size_t)((kb * 2 + ks) * 16 + (nblk << 3) + wave)) << 9) + lane * 8;
        short8 bfr = *(const short8*)bp;
        #pragma unroll
        for (int mt = 0; mt < 4; ++mt)
          acc[mt] = __builtin_amdgcn_mfma_f32_16x16x32_bf16(afr[mt], bfr, acc[mt], 0, 0, 0);
      }
    }
    __syncthreads();
  }
  {
    int col = (nblk << 7) + (wave << 4) + m;
    float sacc = 0.f, ssacc = 0.f;
    #pragma unroll
    for (int mt = 0; mt < 4; ++mt) {
      f32x4 v4 = acc[mt];
      sacc += v4[0] + v4[1] + v4[2] + v4[3];
      ssacc += v4[0] * v4[0] + v4[1] * v4[1] + v4[2] * v4[2] + v4[3] * v4[3];
      // transposed write: (b, col, n) with n = n0 + mt*16 + quad*4 .. +3
      *(f32x4*)&yrawT[(((size_t)(b << 8) + col) << 11) + n0 + mt * 16 + quad * 4] = v4;
    }
    sacc += __shfl_xor(sacc, 16);  sacc += __shfl_xor(sacc, 32);
    ssacc += __shfl_xor(ssacc, 16); ssacc += __shfl_xor(ssacc, 32);
    if (quad == 0) {
      atomicAdd(&stats[col], sacc);
      atomicAdd(&stats[256 + col], ssacc);
    }
  }
}

// ---------------- BN2 + relu, v4: pure streaming elementwise on the
// (b,c,n)-transposed yraw (conv2 writes it transposed now) ----------------
__global__ __launch_bounds__(256) void out_kernel(const float* __restrict__ yrawT,
                                                  const float* __restrict__ stats2,
                                                  const float* __restrict__ g2,
                                                  const float* __restrict__ be2,
                                                  float* __restrict__ out) {
  __shared__ float c2A[256], c2B[256];
  int tid = threadIdx.x;
  {
    float mm = stats2[tid] * (1.f / 16384.f);
    float var = stats2[256 + tid] * (1.f / 16384.f) - mm * mm;
    float a = g2[tid] * rsqrtf(var + 1e-5f);
    c2A[tid] = a;
    c2B[tid] = be2[tid] - mm * a;
  }
  __syncthreads();
  #pragma unroll
  for (int it = 0; it < 4; ++it) {
    size_t i4 = (size_t)blockIdx.x * 1024 + it * 256 + tid;  // float4 index
    int c = (int)((i4 >> 9) & 255);
    float a = c2A[c], be = c2B[c];
    float4 v = *(const float4*)&yrawT[i4 << 2];
    float t0 = a * v.x + be, t1 = a * v.y + be;
    float t2 = a * v.z + be, t3 = a * v.w + be;
    v.x = t0 > 0.f ? t0 : 0.f;
    v.y = t1 > 0.f ? t1 : 0.f;
    v.z = t2 > 0.f ? t2 : 0.f;
    v.w = t3 > 0.f ? t3 : 0.f;
    *(float4*)&out[i4 << 2] = v;
  }
}

extern "C" void kernel_launch(void* const* d_in, const int* in_sizes, int n_in,
                              void* d_out, int out_size, void* d_ws, size_t ws_size,
                              hipStream_t stream) {
  const float* x   = (const float*)d_in[0];
  const float* w1  = (const float*)d_in[1];
  const float* g1  = (const float*)d_in[3];
  const float* be1 = (const float*)d_in[4];
  const float* w2  = (const float*)d_in[5];
  const float* g2  = (const float*)d_in[7];
  const float* be2 = (const float*)d_in[8];
  float* out = (float*)d_out;
  char* w = (char*)d_ws;
  // workspace layout (~106.6 MB total)
  float* sqf    = (float*)(w);                 // 16384 * 4 (slot 131072 B)
  int*  idxbuf  = (int*)(w + 131072);          // 327680 * 4     = 1310720
  uint* hu      = (uint*)(w + 1441792);        // h bf16: 83886080 B
  float* xtf    = (float*)(w + 1441792);       // fp32 xT, 8 MB — ALIASES hu
  int*  cbuf    = (int*)(w + 9830400);         // 16384*64*4 = 4 MB — ALIASES hu
                                               // (xtf/cbuf dead before conv1)
  float* yraw   = (float*)(w + 85327872);      // 4194304 * 4    = 16777216
  float* stats  = (float*)(w + 102105088);     // 4 * 256 floats
  ushort* wp1   = (ushort*)(w + 102113280);    // 196608 * 2 = 393216
  ushort* wpack = (ushort*)(w + 102506496);    // 999424 * 2 = 1998848
  ushort* xbf_t = (ushort*)(w + 104505344);    // 1048576 * 2 -> end 106602496

  hipMemsetAsync(stats, 0, 4096, stream);
  prep_transpose<<<4928, 256, 0, stream>>>(w1, w2, wp1, wpack,
                                           x, (uint*)xbf_t, xtf, sqf);
  knn_kernel<<<2048, 1024, 0, stream>>>(xbf_t, sqf, cbuf);
  knn_merge<<<4096, 256, 0, stream>>>(xtf, cbuf, idxbuf);
  conv1_mfma<<<1024, 512, 0, stream>>>(xbf_t, idxbuf, wp1, hu, stats);
  conv2_mfma<<<512, 512, 0, stream>>>(xbf_t, idxbuf, hu, stats, g1, be1,
                                      wpack, yraw, stats + 512);
  out_kernel<<<1024, 256, 0, stream>>>(yraw, stats + 512, g2, be2, out);
}

// Round 17
// 292.726 us; speedup vs baseline: 1.0015x; 1.0015x over previous
//
#include <hip/hip_runtime.h>
#include <stdint.h>

typedef unsigned int uint;
typedef unsigned short ushort;
typedef __attribute__((ext_vector_type(8))) short short8;
typedef __attribute__((ext_vector_type(4))) float f32x4;

__device__ __forceinline__ uint f2bf(float f) {
  uint u = __float_as_uint(f);
  return (u + 0x7fffu + ((u >> 16) & 1u)) >> 16;
}
__device__ __forceinline__ float bf2f(uint us) {
  return __uint_as_float(us << 16);
}
__device__ __forceinline__ uint cvtpk_bf16(float lo, float hi) {
  uint r;
  asm("v_cvt_pk_bf16_f32 %0, %1, %2" : "=v"(r) : "v"(lo), "v"(hi));
  return r;
}
__device__ __forceinline__ int lt_count(unsigned long long m) {
  return (int)__builtin_amdgcn_mbcnt_hi((uint)(m >> 32),
             __builtin_amdgcn_mbcnt_lo((uint)m, 0u));
}

// ---------------- fused: weight preprocessing + x transpose ----------------
// blocks 0..255: transpose_x (bf16 xT + fp32 xT + sqnorm).
// blocks 256..4927: prep_weights (wp1 + wpack), g = (blk-256)*256+tid.
__global__ __launch_bounds__(256) void prep_transpose(
    const float* __restrict__ w1, const float* __restrict__ w2,
    ushort* __restrict__ wp1, ushort* __restrict__ wpack,
    const float* __restrict__ x, uint* __restrict__ xtu,
    float* __restrict__ xtf, float* __restrict__ sqf) {
  __shared__ float t[64][65];
  int tid = threadIdx.x;
  if (blockIdx.x >= 256) {
    int g = (blockIdx.x - 256) * 256 + tid;
    if (g < 196608) {
      int chunk = g >> 9;            // (t*2+ks)*16 + ctile
      int r = g & 511;
      int lane = r >> 3, j = r & 7;
      int tks = chunk >> 4;
      int ctile = chunk & 15;
      int tt0 = tks >> 1, ks = tks & 1;
      int c = ctile * 16 + (lane & 15);
      int d = ks * 32 + ((lane >> 4) << 3) + j;
      float val;
      if (tt0 < 11) {
        val = w1[c * 1408 + (64 + d) * 11 + tt0];
      } else {
        float s = 0.f;
        for (int tt = 0; tt < 11; ++tt)
          s += w1[c * 1408 + d * 11 + tt] - w1[c * 1408 + (64 + d) * 11 + tt];
        val = s;
      }
      wp1[g] = (ushort)f2bf(val);
    } else {
      int gp = g - 196608;            // < 999424 = 61*16384
      int chunk = gp >> 9;            // (kb*2+ks)*16 + ctile
      int r = gp & 511;
      int lane = r >> 3, j = r & 7;
      int kb = chunk >> 5;
      int rem = chunk & 31;
      int ks = rem >> 4, ctile = rem & 15;
      int c = ctile * 16 + (lane & 15);
      int k = kb * 64 + ks * 32 + ((lane >> 4) << 3) + j;
      float val;
      if (k < 64) {
        int d = k;
        float s = 0.f;
        for (int jn = 0; jn < 20; ++jn)
          s += w2[c * 5120 + d * 40 + jn] - w2[c * 5120 + (64 + d) * 40 + jn];
        val = s;
      } else if (k < 1344) {
        int q = k - 64; int jn = q >> 6, d = q & 63;
        val = w2[c * 5120 + (64 + d) * 40 + jn];
      } else {
        int q = k - 1344; int ci = q / 20, jj = q - ci * 20;
        val = w2[c * 5120 + ci * 40 + 20 + jj];
      }
      wpack[gp] = (ushort)f2bf(val);
    }
    return;
  }
  // ---- transpose part (manual f2bf kept: feeds kNN ranking) ----
  int blk = blockIdx.x;            // 256 = 8 b x 32 n-tiles
  int b = blk >> 5, n0 = (blk & 31) << 6;
  const float* xb = x + b * 131072;
  #pragma unroll
  for (int it = 0; it < 16; ++it) {
    int d = (it << 2) + (tid >> 6);
    int n = tid & 63;
    t[d][n] = xb[d * 2048 + n0 + n];
  }
  __syncthreads();
  #pragma unroll
  for (int it = 0; it < 8; ++it) {
    int n = (it << 3) + (tid >> 5);
    int dp = tid & 31;
    float f0 = t[2 * dp][n], f1 = t[2 * dp + 1][n];
    uint v = f2bf(f0) | (f2bf(f1) << 16);
    size_t col = (size_t)(b * 2048 + n0 + n);
    xtu[col * 32 + dp] = v;
    float2 fv; fv.x = f0; fv.y = f1;
    *(float2*)&xtf[(col << 6) + 2 * dp] = fv;
    float s = f0 * f0 + f1 * f1;
    #pragma unroll
    for (int off = 16; off > 0; off >>= 1) s += __shfl_xor(s, off);
    if (dp == 0) sqf[col] = s;
  }
}

// ---------------- kNN v10: threshold + compact + rank; dist rows padded to
// 1040 (stride % 32 banks = 16) so the 4 quads' writes are 2-way not 4-way
// (2-way is free per m136). 75 KB LDS -> still 2 blocks/CU. ----------------
__global__ __launch_bounds__(1024) void knn_kernel(
    const ushort* __restrict__ xbf_t, const float* __restrict__ sqf,
    int* __restrict__ cbuf) {
  __shared__ uint dist[16][1040];   // 66560 B (padded rows)
  __shared__ uint surv[16][132];    // 8448 B (128 max survivors + pad)
  int tid = threadIdx.x;
  int wv = tid >> 6, lane = tid & 63;
  int grp = blockIdx.x >> 1;
  int half = blockIdx.x & 1;
  int cbase = half << 10;
  int row0 = grp << 4;
  int b = row0 >> 11, n0 = row0 & 2047;
  const ushort* xt = xbf_t + ((size_t)b << 17);
  const float* sqb = sqf + (b << 11);
  int m = lane & 15, quad = lane >> 4;
  short8 afr0 = *(const short8*)(xt + ((size_t)(n0 + m) << 6) + quad * 8);
  short8 afr1 = *(const short8*)(xt + ((size_t)(n0 + m) << 6) + 32 + quad * 8);
  for (int t = 0; t < 4; ++t) {
    int lcol = (((wv << 2) + t) << 4) + m;
    int col = cbase + lcol;
    short8 bfr0 = *(const short8*)(xt + ((size_t)col << 6) + quad * 8);
    short8 bfr1 = *(const short8*)(xt + ((size_t)col << 6) + 32 + quad * 8);
    f32x4 c = {};
    c = __builtin_amdgcn_mfma_f32_16x16x32_bf16(afr0, bfr0, c, 0, 0, 0);
    c = __builtin_amdgcn_mfma_f32_16x16x32_bf16(afr1, bfr1, c, 0, 0, 0);
    float sq = sqb[col];
    #pragma unroll
    for (int r = 0; r < 4; ++r) {
      float f = sq - 2.f * c[r];
      uint u = __float_as_uint(f);
      uint srt = u ^ ((uint)((int)u >> 31) | 0x80000000u);
      dist[quad * 4 + r][lcol] = (srt & 0xFFFFF800u) | (uint)col;
    }
  }
  __syncthreads();
  uint* dr = dist[wv];
  int selfl = (n0 + wv) - cbase;
  if (selfl >= 0 && selfl < 1024 && ((selfl & 63) == lane))
    dr[selfl] = 0xFFFFFFFFu;

  // phase 1: load this lane's 16 keys to registers, track lane min
  uint key[16];
  uint v0 = 0xFFFFFFFFu;
  #pragma unroll
  for (int l = 0; l < 16; ++l) {
    uint v = dr[(l << 6) + lane];
    key[l] = v;
    v0 = v0 < v ? v0 : v;
  }

  // phase 2: bitonic sort of the 64 lane-minima across lanes; T = element 31
  uint s = v0;
  #pragma unroll
  for (int k = 2; k <= 64; k <<= 1) {
    #pragma unroll
    for (int j = k >> 1; j > 0; j >>= 1) {
      uint o = (uint)__shfl_xor((int)s, j);
      bool up = ((lane & k) == 0);
      bool lower = ((lane & j) == 0);
      uint mn = s < o ? s : o;
      uint mx = s < o ? o : s;
      s = (lower == up) ? mn : mx;
    }
  }
  uint T = (uint)__shfl((int)s, 31);

  // phase 3: ballot-compact survivors (key <= T) into surv[wv]
  int base = 0;
  #pragma unroll
  for (int l = 0; l < 16; ++l) {
    uint v = key[l];
    bool f = (v <= T);
    unsigned long long mk = __ballot(f);
    if (f) {
      int pos = base + lt_count(mk);
      if (pos < 128) surv[wv][pos] = v;
    }
    base += __popcll(mk);
  }
  int S = base < 128 ? base : 128;
  if (lane < 4) surv[wv][S + lane] = 0xFFFFFFFFu;   // pad for b128 tail read

  // phase 4: exact rank of each survivor = count of strictly-smaller survivors
  int outb = (row0 + wv) * 64 + (half << 5);
  uint k0 = (lane < S) ? surv[wv][lane] : 0xFFFFFFFFu;
  int r0 = 0;
  if (S > 64) {
    uint k1 = (lane + 64 < S) ? surv[wv][lane + 64] : 0xFFFFFFFFu;
    int r1 = 0;
    for (int i = 0; i < S; i += 4) {
      uint4 q = *(const uint4*)&surv[wv][i];   // broadcast read
      r0 += (q.x < k0) + (q.y < k0) + (q.z < k0) + (q.w < k0);
      r1 += (q.x < k1) + (q.y < k1) + (q.z < k1) + (q.w < k1);
    }
    if (lane + 64 < S && r1 < 32) cbuf[outb + r1] = (int)(k1 & 2047u);
  } else {
    for (int i = 0; i < S; i += 4) {
      uint4 q = *(const uint4*)&surv[wv][i];   // broadcast read
      r0 += (q.x < k0) + (q.y < k0) + (q.z < k0) + (q.w < k0);
    }
  }
  if (lane < S && r0 < 32) cbuf[outb + r0] = (int)(k0 & 2047u);
}

// ---------------- kNN merge: fp64 exact re-rank of 64 candidates/row ----------------
__global__ __launch_bounds__(256) void knn_merge(
    const float* __restrict__ xtf, const int* __restrict__ cbuf,
    int* __restrict__ idxout) {
  __shared__ double dkey[4][64];
  __shared__ int ccol[4][64];
  int tid = threadIdx.x;
  int wv = tid >> 6, lane = tid & 63;
  int row = (blockIdx.x << 2) + wv;
  int b = row >> 11, n = row & 2047;
  int ci = cbuf[row * 64 + lane];
  const float* xc = xtf + ((size_t)b << 17);
  const float4* xj4 = (const float4*)(xc + ((size_t)ci << 6));
  const float4* xi4 = (const float4*)(xc + ((size_t)n << 6));
  double dt = 0.0, s2 = 0.0;
  #pragma unroll 4
  for (int d4 = 0; d4 < 16; ++d4) {
    float4 vj = xj4[d4];
    float4 vi = xi4[d4];
    double a0 = (double)vj.x, a1 = (double)vj.y, a2 = (double)vj.z, a3 = (double)vj.w;
    s2 += a0 * a0 + a1 * a1 + a2 * a2 + a3 * a3;
    dt += (double)vi.x * a0 + (double)vi.y * a1 + (double)vi.z * a2 + (double)vi.w * a3;
  }
  dkey[wv][lane] = s2 - 2.0 * dt;
  ccol[wv][lane] = ci;
  __syncthreads();
  double kl = dkey[wv][lane];
  int rank = 0;
  for (int mm = 0; mm < 64; ++mm) {
    double km = dkey[wv][mm];
    int cm = ccol[wv][mm];
    if (km < kl || (km == kl && cm < ci)) ++rank;
  }
  if (rank < 20) idxout[row * 20 + rank] = ci;
}

// ---------------- conv1 as bf16 MFMA v5 + cvt_pk epilogue:
// 8-wave blocks (2 ctile passes/wave), chunk-major XOR-swizzled LDS.
// (v6 tap-split REVERTED: 6-waves/SIMD cap spilled acc — reg floor ~90.)
// Block: 16 points x 256 channels (8 waves; pass p: ctile = p*8+wave).
// LDS sl[s][chunk][p^chunk][8]: chunk = ks*4+quad (conflict-free, R6). ----------------
__global__ __launch_bounds__(512, 4) void conv1_mfma(
    const ushort* __restrict__ xbf_t, const int* __restrict__ idxbuf,
    const ushort* __restrict__ wp1, uint* __restrict__ hu,
    float* __restrict__ stats) {
  __shared__ ushort sl[21][8][16][8];   // 43008 B
  __shared__ int nidx[16][20];
  int tid = threadIdx.x;
  int p0 = blockIdx.x << 4;
  int b = p0 >> 11, n0 = p0 & 2047;
  const ushort* xt = xbf_t + ((size_t)b << 17);
  for (int v = tid; v < 320; v += 512) {
    int p = v / 20, j = v - p * 20;
    nidx[p][j] = idxbuf[(p0 + p) * 20 + j];
  }
  __syncthreads();
  for (int v = tid; v < 2688; v += 512) {
    int s = v >> 7;
    int r = v & 127;
    int p = r >> 3, i = r & 7;
    int col = (s == 0) ? (n0 + p) : nidx[p][s - 1];
    *(short8*)&sl[s][i][p ^ i][0] =
        *(const short8*)(xt + ((size_t)col << 6) + (i << 3));
  }
  __syncthreads();
  int lane = tid & 63, wave = tid >> 6;   // wave 0..7
  int m = lane & 15, quad = lane >> 4;
  #pragma unroll 1
  for (int pass = 0; pass < 2; ++pass) {
    int ctile = (pass << 3) + wave;
    int c = ctile * 16 + m;
    f32x4 acc[10] = {};
    f32x4 cacc = {};
    // ks-split: only 12 B-fragments (tb[11]+ub, 48 VGPRs) live at a time
    #pragma unroll 1
    for (int ks = 0; ks < 2; ++ks) {
      int cch = ks * 4 + quad;          // LDS chunk for this lane
      int ms = m ^ cch;                 // XOR-swizzled point slot
      short8 tb[11];
      #pragma unroll
      for (int t = 0; t < 11; ++t)
        tb[t] = *(const short8*)(wp1 + (((t * 2 + ks) * 16 + ctile) << 9) + lane * 8);
      short8 ub = *(const short8*)(wp1 + (((22 + ks) * 16 + ctile) << 9) + lane * 8);
      {
        short8 a = *(const short8*)&sl[0][cch][ms][0];
        cacc = __builtin_amdgcn_mfma_f32_16x16x32_bf16(a, ub, cacc, 0, 0, 0);
      }
      // slice-outer: read each slice once, accumulate into all valid ko = s-1-t
      #pragma unroll
      for (int s = 1; s <= 20; ++s) {
        short8 a = *(const short8*)&sl[s][cch][ms][0];
        #pragma unroll
        for (int t = 0; t < 11; ++t) {
          int ko = s - 1 - t;
          if (ko >= 0 && ko < 10)
            acc[ko] = __builtin_amdgcn_mfma_f32_16x16x32_bf16(a, tb[t], acc[ko], 0, 0, 0);
        }
      }
    }
    // epilogue: D col=lane&15 -> channel, row=quad*4+r -> point; fused stats
    float sacc = 0.f, ssacc = 0.f;
    #pragma unroll
    for (int r = 0; r < 4; ++r) {
      int p = (quad << 2) + r;
      int base5 = ((p0 + p) * 256 + c) * 5;
      float cc = cacc[r];
      #pragma unroll
      for (int q = 0; q < 5; ++q) {
        float f0 = acc[2 * q][r] + cc;
        float f1 = acc[2 * q + 1][r] + cc;
        sacc += f0 + f1;
        ssacc += f0 * f0 + f1 * f1;
        hu[base5 + q] = cvtpk_bf16(f0, f1);   // RNE pack, 1 instr vs ~7
      }
    }
    sacc += __shfl_xor(sacc, 16);  sacc += __shfl_xor(sacc, 32);
    ssacc += __shfl_xor(ssacc, 16); ssacc += __shfl_xor(ssacc, 32);
    if (quad == 0) {
      atomicAdd(&stats[c], sacc);
      atomicAdd(&stats[256 + c], ssacc);
    }
  }
}

// ---------------- conv2 as bf16 MFMA GEMM v10: M=64 x N=128 tiles
// (grid 512 = 2 blocks/CU, no tail). BN1 coefs computed IN-KERNEL from
// conv1 stats (kills the 1-block finalize launch; identical fp32 ops ->
// bit-identical). Dequant path = R12-measured form. R8 XOR swizzle kept. ----------------
__global__ __launch_bounds__(512, 4) void conv2_mfma(
    const ushort* __restrict__ xbf_t, const int* __restrict__ idxbuf,
    const uint* __restrict__ hu, const float* __restrict__ stats1,
    const float* __restrict__ g1, const float* __restrict__ be1,
    const ushort* __restrict__ wpack, float* __restrict__ yraw,
    float* __restrict__ stats) {
  __shared__ ushort As[2][4][64][64];   // 65536 B (swizzled)
  __shared__ int nidx[64][20];          // 5120 B
  __shared__ float cfA[257], cfB[257];  // 2056 B -> total 72712 B
  int tid = threadIdx.x;
  int nblk = blockIdx.x & 1;            // N-half: cols nblk*128..+127
  int p0 = (blockIdx.x >> 1) << 6;      // 64 points per block
  int b = p0 >> 11, n0 = p0 & 2047;
  const ushort* xt = xbf_t + ((size_t)b << 17);

  if (tid < 256) {
    float mm = stats1[tid] * (1.f / 163840.f);
    float var = stats1[256 + tid] * (1.f / 163840.f) - mm * mm;
    float a = g1[tid] * rsqrtf(var + 1e-5f);
    cfA[tid] = a;
    cfB[tid] = be1[tid] - mm * a;
    if (tid == 0) { cfA[256] = 0.f; cfB[256] = 0.f; }
  }
  for (int v = tid; v < 1280; v += 512) {
    int p = v / 20, j = v - p * 20;
    nidx[p][j] = idxbuf[(p0 + p) * 20 + j];
  }
  __syncthreads();

  int pp = tid >> 3;                 // point 0..63
  int t7 = tid & 7;
  int off = t7 << 3;                 // logical 8-col chunk within 64
  int wroff = ((t7 ^ (pp & 7)) << 3);  // swizzled write offset (ushorts)

  auto build = [&](int phase, int buf) {
    int kb0 = phase << 2;
    short8 xv[4];
    uint4 hv[4];
    #pragma unroll
    for (int kc = 0; kc < 4; ++kc) {
      int kb = kb0 + kc;
      if (kb >= 61) continue;
      if (kb < 21) {
        int col = (kb == 0) ? (n0 + pp) : nidx[pp][kb - 1];
        xv[kc] = *(const short8*)(xt + ((size_t)col << 6) + off);
      } else {
        int q0 = (kb - 21) * 64 + off;
        hv[kc] = *(const uint4*)(hu + (size_t)(p0 + pp) * 1280 + (q0 >> 1));
      }
    }
    #pragma unroll
    for (int kc = 0; kc < 4; ++kc) {
      int kb = kb0 + kc;
      if (kb >= 61) continue;
      if (kb < 21) {
        *(short8*)&As[buf][kc][pp][wroff] = xv[kc];
      } else {
        int q0 = (kb - 21) * 64 + off;
        uint4 hvv = hv[kc];
        float f[8];
        f[0] = bf2f(hvv.x & 0xffffu); f[1] = bf2f(hvv.x >> 16);
        f[2] = bf2f(hvv.y & 0xffffu); f[3] = bf2f(hvv.y >> 16);
        f[4] = bf2f(hvv.z & 0xffffu); f[5] = bf2f(hvv.z >> 16);
        f[6] = bf2f(hvv.w & 0xffffu); f[7] = bf2f(hvv.w >> 16);
        int ch0 = q0 / 10;
        int rem = q0 - ch0 * 10;      // one magic-div per 8 elements
        float a0 = cfA[ch0], b0 = cfB[ch0];
        float a1 = cfA[ch0 + 1], b1 = cfB[ch0 + 1];
        uint4 wv4;
        uint rr[4];
        #pragma unroll
        for (int i = 0; i < 4; ++i) {
          bool hlo = (rem + 2 * i) >= 10;
          bool hhi = (rem + 2 * i + 1) >= 10;
          float vlo = f[2 * i]     * (hlo ? a1 : a0) + (hlo ? b1 : b0);
          float vhi = f[2 * i + 1] * (hhi ? a1 : a0) + (hhi ? b1 : b0);
          vlo = fmaxf(vlo, 0.01f * vlo);   // leaky: identical result, 2 ops
          vhi = fmaxf(vhi, 0.01f * vhi);
          rr[i] = cvtpk_bf16(vlo, vhi);    // RNE pack, 1 instr per pair
        }
        wv4.x = rr[0]; wv4.y = rr[1]; wv4.z = rr[2]; wv4.w = rr[3];
        *(uint4*)&As[buf][kc][pp][wroff] = wv4;
      }
    }
  };

  int lane = tid & 63, wave = tid >> 6;
  int m = lane & 15, quad = lane >> 4;
  // swizzled read chunk offsets (ushorts) for ks=0,1 — R8-verified pattern
  int rdoff0 = ((quad ^ (m & 7)) << 3);
  int rdoff1 = (((4 + quad) ^ (m & 7)) << 3);
  f32x4 acc[4] = {};

  build(0, 0);
  __syncthreads();
  for (int phase = 0; phase < 16; ++phase) {
    int buf = phase & 1;
    if (phase < 15) build(phase + 1, buf ^ 1);
    #pragma unroll
    for (int kc = 0; kc < 4; ++kc) {
      int kb = (phase << 2) + kc;
      if (kb >= 61) break;
      #pragma unroll
      for (int ks = 0; ks < 2; ++ks) {
        int rdoff = ks ? rdoff1 : rdoff0;
        short8 afr[4];
        #pragma unroll
        for (int mt = 0; mt < 4; ++mt)
          afr[mt] = *(const short8*)&As[buf][kc][mt * 16 + m][rdoff];
        const ushort* bp = wpack +
            (((size_t)((kb * 2 + ks) * 16 + (nblk << 3) + wave)) << 9) + lane * 8;
        short8 bfr = *(const short8*)bp;
        #pragma unroll
        for (int mt = 0; mt < 4; ++mt)
          acc[mt] = __builtin_amdgcn_mfma_f32_16x16x32_bf16(afr[mt], bfr, acc[mt], 0, 0, 0);
      }
    }
    __syncthreads();
  }
  {
    int col = (nblk << 7) + (wave << 4) + m;
    float sacc = 0.f, ssacc = 0.f;
    #pragma unroll
    for (int mt = 0; mt < 4; ++mt) {
      #pragma unroll
      for (int r = 0; r < 4; ++r) {
        int prow = mt * 16 + quad * 4 + r;
        float v = acc[mt][r];
        sacc += v; ssacc += v * v;
        yraw[(size_t)(p0 + prow) * 256 + col] = v;
      }
    }
    sacc += __shfl_xor(sacc, 16);  sacc += __shfl_xor(sacc, 32);
    ssacc += __shfl_xor(ssacc, 16); ssacc += __shfl_xor(ssacc, 32);
    if (quad == 0) {
      atomicAdd(&stats[col], sacc);
      atomicAdd(&stats[256 + col], ssacc);
    }
  }
}

// ---------------- BN2 + relu + transpose to (b, c, n), v3: float4 stores +
// BN2 coefs computed in-kernel from conv2 stats (kills finalize launch) ----------------
__global__ __launch_bounds__(256) void out_kernel(const float* __restrict__ yraw,
                                                  const float* __restrict__ stats2,
                                                  const float* __restrict__ g2,
                                                  const float* __restrict__ be2,
                                                  float* __restrict__ out) {
  __shared__ float t[64][257];
  __shared__ float c2A[256], c2B[256];
  int tid = threadIdx.x;
  int blk = blockIdx.x;            // 256 = 8 b x 32 n-tiles
  int b = blk >> 5, n0 = (blk & 31) << 6;
  {
    float mm = stats2[tid] * (1.f / 16384.f);
    float var = stats2[256 + tid] * (1.f / 16384.f) - mm * mm;
    float a = g2[tid] * rsqrtf(var + 1e-5f);
    c2A[tid] = a;
    c2B[tid] = be2[tid] - mm * a;
  }
  for (int it = 0; it < 64; ++it)
    t[it][tid] = yraw[(b * 2048 + n0 + it) * 256 + tid];
  __syncthreads();
  int nsub4 = (tid & 15) << 2;
  int cq = tid >> 4;               // 0..15
  for (int it = 0; it < 16; ++it) {
    int c = (it << 4) + cq;
    float a = c2A[c], be = c2B[c];
    float4 v;
    v.x = a * t[nsub4 + 0][c] + be;
    v.y = a * t[nsub4 + 1][c] + be;
    v.z = a * t[nsub4 + 2][c] + be;
    v.w = a * t[nsub4 + 3][c] + be;
    v.x = v.x > 0.f ? v.x : 0.f;
    v.y = v.y > 0.f ? v.y : 0.f;
    v.z = v.z > 0.f ? v.z : 0.f;
    v.w = v.w > 0.f ? v.w : 0.f;
    *(float4*)&out[(size_t)(b * 256 + c) * 2048 + n0 + nsub4] = v;
  }
}

extern "C" void kernel_launch(void* const* d_in, const int* in_sizes, int n_in,
                              void* d_out, int out_size, void* d_ws, size_t ws_size,
                              hipStream_t stream) {
  const float* x   = (const float*)d_in[0];
  const float* w1  = (const float*)d_in[1];
  const float* g1  = (const float*)d_in[3];
  const float* be1 = (const float*)d_in[4];
  const float* w2  = (const float*)d_in[5];
  const float* g2  = (const float*)d_in[7];
  const float* be2 = (const float*)d_in[8];
  float* out = (float*)d_out;
  char* w = (char*)d_ws;
  // workspace layout (~106.6 MB total)
  float* sqf    = (float*)(w);                 // 16384 * 4 (slot 131072 B)
  int*  idxbuf  = (int*)(w + 131072);          // 327680 * 4     = 1310720
  uint* hu      = (uint*)(w + 1441792);        // h bf16: 83886080 B
  float* xtf    = (float*)(w + 1441792);       // fp32 xT, 8 MB — ALIASES hu
  int*  cbuf    = (int*)(w + 9830400);         // 16384*64*4 = 4 MB — ALIASES hu
                                               // (xtf/cbuf dead before conv1)
  float* yraw   = (float*)(w + 85327872);      // 4194304 * 4    = 16777216
  float* stats  = (float*)(w + 102105088);     // 4 * 256 floats
  ushort* wp1   = (ushort*)(w + 102113280);    // 196608 * 2 = 393216
  ushort* wpack = (ushort*)(w + 102506496);    // 999424 * 2 = 1998848
  ushort* xbf_t = (ushort*)(w + 104505344);    // 1048576 * 2 -> end 106602496

  hipMemsetAsync(stats, 0, 4096, stream);
  prep_transpose<<<4928, 256, 0, stream>>>(w1, w2, wp1, wpack,
                                           x, (uint*)xbf_t, xtf, sqf);
  knn_kernel<<<2048, 1024, 0, stream>>>(xbf_t, sqf, cbuf);
  knn_merge<<<4096, 256, 0, stream>>>(xtf, cbuf, idxbuf);
  conv1_mfma<<<1024, 512, 0, stream>>>(xbf_t, idxbuf, wp1, hu, stats);
  conv2_mfma<<<512, 512, 0, stream>>>(xbf_t, idxbuf, hu, stats, g1, be1,
                                      wpack, yraw, stats + 512);
  out_kernel<<<256, 256, 0, stream>>>(yraw, stats + 512, g2, be2, out);
}

// Round 18
// 286.780 us; speedup vs baseline: 1.0222x; 1.0207x over previous
//
#include <hip/hip_runtime.h>
#include <stdint.h>

typedef unsigned int uint;
typedef unsigned short ushort;
typedef __attribute__((ext_vector_type(8))) short short8;
typedef __attribute__((ext_vector_type(4))) float f32x4;

__device__ __forceinline__ uint f2bf(float f) {
  uint u = __float_as_uint(f);
  return (u + 0x7fffu + ((u >> 16) & 1u)) >> 16;
}
__device__ __forceinline__ float bf2f(uint us) {
  return __uint_as_float(us << 16);
}
__device__ __forceinline__ uint cvtpk_bf16(float lo, float hi) {
  uint r;
  asm("v_cvt_pk_bf16_f32 %0, %1, %2" : "=v"(r) : "v"(lo), "v"(hi));
  return r;
}
__device__ __forceinline__ int lt_count(unsigned long long m) {
  return (int)__builtin_amdgcn_mbcnt_hi((uint)(m >> 32),
             __builtin_amdgcn_mbcnt_lo((uint)m, 0u));
}

// ---------------- fused: weight preprocessing + x transpose ----------------
// blocks 0..255: transpose_x (bf16 xT + fp32 xT + sqnorm).
// blocks 256..4927: prep_weights (wp1 + wpack), g = (blk-256)*256+tid.
__global__ __launch_bounds__(256) void prep_transpose(
    const float* __restrict__ w1, const float* __restrict__ w2,
    ushort* __restrict__ wp1, ushort* __restrict__ wpack,
    const float* __restrict__ x, uint* __restrict__ xtu,
    float* __restrict__ xtf, float* __restrict__ sqf) {
  __shared__ float t[64][65];
  int tid = threadIdx.x;
  if (blockIdx.x >= 256) {
    int g = (blockIdx.x - 256) * 256 + tid;
    if (g < 196608) {
      int chunk = g >> 9;            // (t*2+ks)*16 + ctile
      int r = g & 511;
      int lane = r >> 3, j = r & 7;
      int tks = chunk >> 4;
      int ctile = chunk & 15;
      int tt0 = tks >> 1, ks = tks & 1;
      int c = ctile * 16 + (lane & 15);
      int d = ks * 32 + ((lane >> 4) << 3) + j;
      float val;
      if (tt0 < 11) {
        val = w1[c * 1408 + (64 + d) * 11 + tt0];
      } else {
        float s = 0.f;
        for (int tt = 0; tt < 11; ++tt)
          s += w1[c * 1408 + d * 11 + tt] - w1[c * 1408 + (64 + d) * 11 + tt];
        val = s;
      }
      wp1[g] = (ushort)f2bf(val);
    } else {
      int gp = g - 196608;            // < 999424 = 61*16384
      int chunk = gp >> 9;            // (kb*2+ks)*16 + ctile
      int r = gp & 511;
      int lane = r >> 3, j = r & 7;
      int kb = chunk >> 5;
      int rem = chunk & 31;
      int ks = rem >> 4, ctile = rem & 15;
      int c = ctile * 16 + (lane & 15);
      int k = kb * 64 + ks * 32 + ((lane >> 4) << 3) + j;
      float val;
      if (k < 64) {
        int d = k;
        float s = 0.f;
        for (int jn = 0; jn < 20; ++jn)
          s += w2[c * 5120 + d * 40 + jn] - w2[c * 5120 + (64 + d) * 40 + jn];
        val = s;
      } else if (k < 1344) {
        int q = k - 64; int jn = q >> 6, d = q & 63;
        val = w2[c * 5120 + (64 + d) * 40 + jn];
      } else {
        int q = k - 1344; int ci = q / 20, jj = q - ci * 20;
        val = w2[c * 5120 + ci * 40 + 20 + jj];
      }
      wpack[gp] = (ushort)f2bf(val);
    }
    return;
  }
  // ---- transpose part (manual f2bf kept: feeds kNN ranking) ----
  int blk = blockIdx.x;            // 256 = 8 b x 32 n-tiles
  int b = blk >> 5, n0 = (blk & 31) << 6;
  const float* xb = x + b * 131072;
  #pragma unroll
  for (int it = 0; it < 16; ++it) {
    int d = (it << 2) + (tid >> 6);
    int n = tid & 63;
    t[d][n] = xb[d * 2048 + n0 + n];
  }
  __syncthreads();
  #pragma unroll
  for (int it = 0; it < 8; ++it) {
    int n = (it << 3) + (tid >> 5);
    int dp = tid & 31;
    float f0 = t[2 * dp][n], f1 = t[2 * dp + 1][n];
    uint v = f2bf(f0) | (f2bf(f1) << 16);
    size_t col = (size_t)(b * 2048 + n0 + n);
    xtu[col * 32 + dp] = v;
    float2 fv; fv.x = f0; fv.y = f1;
    *(float2*)&xtf[(col << 6) + 2 * dp] = fv;
    float s = f0 * f0 + f1 * f1;
    #pragma unroll
    for (int off = 16; off > 0; off >>= 1) s += __shfl_xor(s, off);
    if (dp == 0) sqf[col] = s;
  }
}

// ---------------- kNN v10: threshold + compact + rank; dist rows padded to
// 1040 (stride % 32 banks = 16) so the 4 quads' writes are 2-way not 4-way
// (2-way is free per m136). 75 KB LDS -> still 2 blocks/CU. ----------------
__global__ __launch_bounds__(1024) void knn_kernel(
    const ushort* __restrict__ xbf_t, const float* __restrict__ sqf,
    int* __restrict__ cbuf) {
  __shared__ uint dist[16][1040];   // 66560 B (padded rows)
  __shared__ uint surv[16][132];    // 8448 B (128 max survivors + pad)
  int tid = threadIdx.x;
  int wv = tid >> 6, lane = tid & 63;
  int grp = blockIdx.x >> 1;
  int half = blockIdx.x & 1;
  int cbase = half << 10;
  int row0 = grp << 4;
  int b = row0 >> 11, n0 = row0 & 2047;
  const ushort* xt = xbf_t + ((size_t)b << 17);
  const float* sqb = sqf + (b << 11);
  int m = lane & 15, quad = lane >> 4;
  short8 afr0 = *(const short8*)(xt + ((size_t)(n0 + m) << 6) + quad * 8);
  short8 afr1 = *(const short8*)(xt + ((size_t)(n0 + m) << 6) + 32 + quad * 8);
  for (int t = 0; t < 4; ++t) {
    int lcol = (((wv << 2) + t) << 4) + m;
    int col = cbase + lcol;
    short8 bfr0 = *(const short8*)(xt + ((size_t)col << 6) + quad * 8);
    short8 bfr1 = *(const short8*)(xt + ((size_t)col << 6) + 32 + quad * 8);
    f32x4 c = {};
    c = __builtin_amdgcn_mfma_f32_16x16x32_bf16(afr0, bfr0, c, 0, 0, 0);
    c = __builtin_amdgcn_mfma_f32_16x16x32_bf16(afr1, bfr1, c, 0, 0, 0);
    float sq = sqb[col];
    #pragma unroll
    for (int r = 0; r < 4; ++r) {
      float f = sq - 2.f * c[r];
      uint u = __float_as_uint(f);
      uint srt = u ^ ((uint)((int)u >> 31) | 0x80000000u);
      dist[quad * 4 + r][lcol] = (srt & 0xFFFFF800u) | (uint)col;
    }
  }
  __syncthreads();
  uint* dr = dist[wv];
  int selfl = (n0 + wv) - cbase;
  if (selfl >= 0 && selfl < 1024 && ((selfl & 63) == lane))
    dr[selfl] = 0xFFFFFFFFu;

  // phase 1: load this lane's 16 keys to registers, track lane min
  uint key[16];
  uint v0 = 0xFFFFFFFFu;
  #pragma unroll
  for (int l = 0; l < 16; ++l) {
    uint v = dr[(l << 6) + lane];
    key[l] = v;
    v0 = v0 < v ? v0 : v;
  }

  // phase 2: bitonic sort of the 64 lane-minima across lanes; T = element 31
  uint s = v0;
  #pragma unroll
  for (int k = 2; k <= 64; k <<= 1) {
    #pragma unroll
    for (int j = k >> 1; j > 0; j >>= 1) {
      uint o = (uint)__shfl_xor((int)s, j);
      bool up = ((lane & k) == 0);
      bool lower = ((lane & j) == 0);
      uint mn = s < o ? s : o;
      uint mx = s < o ? o : s;
      s = (lower == up) ? mn : mx;
    }
  }
  uint T = (uint)__shfl((int)s, 31);

  // phase 3: ballot-compact survivors (key <= T) into surv[wv]
  int base = 0;
  #pragma unroll
  for (int l = 0; l < 16; ++l) {
    uint v = key[l];
    bool f = (v <= T);
    unsigned long long mk = __ballot(f);
    if (f) {
      int pos = base + lt_count(mk);
      if (pos < 128) surv[wv][pos] = v;
    }
    base += __popcll(mk);
  }
  int S = base < 128 ? base : 128;
  if (lane < 4) surv[wv][S + lane] = 0xFFFFFFFFu;   // pad for b128 tail read

  // phase 4: exact rank of each survivor = count of strictly-smaller survivors
  int outb = (row0 + wv) * 64 + (half << 5);
  uint k0 = (lane < S) ? surv[wv][lane] : 0xFFFFFFFFu;
  int r0 = 0;
  if (S > 64) {
    uint k1 = (lane + 64 < S) ? surv[wv][lane + 64] : 0xFFFFFFFFu;
    int r1 = 0;
    for (int i = 0; i < S; i += 4) {
      uint4 q = *(const uint4*)&surv[wv][i];   // broadcast read
      r0 += (q.x < k0) + (q.y < k0) + (q.z < k0) + (q.w < k0);
      r1 += (q.x < k1) + (q.y < k1) + (q.z < k1) + (q.w < k1);
    }
    if (lane + 64 < S && r1 < 32) cbuf[outb + r1] = (int)(k1 & 2047u);
  } else {
    for (int i = 0; i < S; i += 4) {
      uint4 q = *(const uint4*)&surv[wv][i];   // broadcast read
      r0 += (q.x < k0) + (q.y < k0) + (q.z < k0) + (q.w < k0);
    }
  }
  if (lane < S && r0 < 32) cbuf[outb + r0] = (int)(k0 & 2047u);
}

// ---------------- kNN merge: fp64 exact re-rank of 64 candidates/row ----------------
__global__ __launch_bounds__(256) void knn_merge(
    const float* __restrict__ xtf, const int* __restrict__ cbuf,
    int* __restrict__ idxout) {
  __shared__ double dkey[4][64];
  __shared__ int ccol[4][64];
  int tid = threadIdx.x;
  int wv = tid >> 6, lane = tid & 63;
  int row = (blockIdx.x << 2) + wv;
  int b = row >> 11, n = row & 2047;
  int ci = cbuf[row * 64 + lane];
  const float* xc = xtf + ((size_t)b << 17);
  const float4* xj4 = (const float4*)(xc + ((size_t)ci << 6));
  const float4* xi4 = (const float4*)(xc + ((size_t)n << 6));
  double dt = 0.0, s2 = 0.0;
  #pragma unroll 4
  for (int d4 = 0; d4 < 16; ++d4) {
    float4 vj = xj4[d4];
    float4 vi = xi4[d4];
    double a0 = (double)vj.x, a1 = (double)vj.y, a2 = (double)vj.z, a3 = (double)vj.w;
    s2 += a0 * a0 + a1 * a1 + a2 * a2 + a3 * a3;
    dt += (double)vi.x * a0 + (double)vi.y * a1 + (double)vi.z * a2 + (double)vi.w * a3;
  }
  dkey[wv][lane] = s2 - 2.0 * dt;
  ccol[wv][lane] = ci;
  __syncthreads();
  double kl = dkey[wv][lane];
  int rank = 0;
  for (int mm = 0; mm < 64; ++mm) {
    double km = dkey[wv][mm];
    int cm = ccol[wv][mm];
    if (km < kl || (km == kl && cm < ci)) ++rank;
  }
  if (rank < 20) idxout[row * 20 + rank] = ci;
}

// ---------------- conv1 as bf16 MFMA v5 + cvt_pk epilogue:
// 8-wave blocks (2 ctile passes/wave), chunk-major XOR-swizzled LDS.
// (v6 tap-split REVERTED: 6-waves/SIMD cap spilled acc — reg floor ~90.)
// Block: 16 points x 256 channels (8 waves; pass p: ctile = p*8+wave).
// LDS sl[s][chunk][p^chunk][8]: chunk = ks*4+quad (conflict-free, R6). ----------------
__global__ __launch_bounds__(512, 4) void conv1_mfma(
    const ushort* __restrict__ xbf_t, const int* __restrict__ idxbuf,
    const ushort* __restrict__ wp1, uint* __restrict__ hu,
    float* __restrict__ stats) {
  __shared__ ushort sl[21][8][16][8];   // 43008 B
  __shared__ int nidx[16][20];
  int tid = threadIdx.x;
  int p0 = blockIdx.x << 4;
  int b = p0 >> 11, n0 = p0 & 2047;
  const ushort* xt = xbf_t + ((size_t)b << 17);
  for (int v = tid; v < 320; v += 512) {
    int p = v / 20, j = v - p * 20;
    nidx[p][j] = idxbuf[(p0 + p) * 20 + j];
  }
  __syncthreads();
  for (int v = tid; v < 2688; v += 512) {
    int s = v >> 7;
    int r = v & 127;
    int p = r >> 3, i = r & 7;
    int col = (s == 0) ? (n0 + p) : nidx[p][s - 1];
    *(short8*)&sl[s][i][p ^ i][0] =
        *(const short8*)(xt + ((size_t)col << 6) + (i << 3));
  }
  __syncthreads();
  int lane = tid & 63, wave = tid >> 6;   // wave 0..7
  int m = lane & 15, quad = lane >> 4;
  #pragma unroll 1
  for (int pass = 0; pass < 2; ++pass) {
    int ctile = (pass << 3) + wave;
    int c = ctile * 16 + m;
    f32x4 acc[10] = {};
    f32x4 cacc = {};
    // ks-split: only 12 B-fragments (tb[11]+ub, 48 VGPRs) live at a time
    #pragma unroll 1
    for (int ks = 0; ks < 2; ++ks) {
      int cch = ks * 4 + quad;          // LDS chunk for this lane
      int ms = m ^ cch;                 // XOR-swizzled point slot
      short8 tb[11];
      #pragma unroll
      for (int t = 0; t < 11; ++t)
        tb[t] = *(const short8*)(wp1 + (((t * 2 + ks) * 16 + ctile) << 9) + lane * 8);
      short8 ub = *(const short8*)(wp1 + (((22 + ks) * 16 + ctile) << 9) + lane * 8);
      {
        short8 a = *(const short8*)&sl[0][cch][ms][0];
        cacc = __builtin_amdgcn_mfma_f32_16x16x32_bf16(a, ub, cacc, 0, 0, 0);
      }
      // slice-outer: read each slice once, accumulate into all valid ko = s-1-t
      #pragma unroll
      for (int s = 1; s <= 20; ++s) {
        short8 a = *(const short8*)&sl[s][cch][ms][0];
        #pragma unroll
        for (int t = 0; t < 11; ++t) {
          int ko = s - 1 - t;
          if (ko >= 0 && ko < 10)
            acc[ko] = __builtin_amdgcn_mfma_f32_16x16x32_bf16(a, tb[t], acc[ko], 0, 0, 0);
        }
      }
    }
    // epilogue: D col=lane&15 -> channel, row=quad*4+r -> point; fused stats
    float sacc = 0.f, ssacc = 0.f;
    #pragma unroll
    for (int r = 0; r < 4; ++r) {
      int p = (quad << 2) + r;
      int base5 = ((p0 + p) * 256 + c) * 5;
      float cc = cacc[r];
      #pragma unroll
      for (int q = 0; q < 5; ++q) {
        float f0 = acc[2 * q][r] + cc;
        float f1 = acc[2 * q + 1][r] + cc;
        sacc += f0 + f1;
        ssacc += f0 * f0 + f1 * f1;
        hu[base5 + q] = cvtpk_bf16(f0, f1);   // RNE pack, 1 instr vs ~7
      }
    }
    sacc += __shfl_xor(sacc, 16);  sacc += __shfl_xor(sacc, 32);
    ssacc += __shfl_xor(ssacc, 16); ssacc += __shfl_xor(ssacc, 32);
    if (quad == 0) {
      atomicAdd(&stats[c], sacc);
      atomicAdd(&stats[256 + c], ssacc);
    }
  }
}

// ---------------- conv2 as bf16 MFMA GEMM v12: M=64 x N=256 single block
// (grid 256, 1024 thr / 16 waves) — dequant runs ONCE per h element (was 2x
// under the N-half split; dequant was the 47%-VALUBusy hotspot). B-traffic
// unchanged at 0.5 GB; occupancy cap unchanged (16 waves/CU). BN1 coefs
// in-kernel. R8-verified conflict-free 4-col write swizzle
// (((t15>>1)^(pp&7))<<3 | (t15&1)<<2); read swizzle unchanged. ----------------
__global__ __launch_bounds__(1024, 4) void conv2_mfma(
    const ushort* __restrict__ xbf_t, const int* __restrict__ idxbuf,
    const uint* __restrict__ hu, const float* __restrict__ stats1,
    const float* __restrict__ g1, const float* __restrict__ be1,
    const ushort* __restrict__ wpack, float* __restrict__ yraw,
    float* __restrict__ stats) {
  __shared__ ushort As[2][4][64][64];   // 65536 B (swizzled)
  __shared__ int nidx[64][20];          // 5120 B
  __shared__ float cfA[257], cfB[257];  // 2056 B -> total 72712 B
  int tid = threadIdx.x;
  int p0 = blockIdx.x << 6;             // 64 points per block, grid 256
  int b = p0 >> 11, n0 = p0 & 2047;
  const ushort* xt = xbf_t + ((size_t)b << 17);

  if (tid < 256) {
    float mm = stats1[tid] * (1.f / 163840.f);
    float var = stats1[256 + tid] * (1.f / 163840.f) - mm * mm;
    float a = g1[tid] * rsqrtf(var + 1e-5f);
    cfA[tid] = a;
    cfB[tid] = be1[tid] - mm * a;
    if (tid == 0) { cfA[256] = 0.f; cfB[256] = 0.f; }
  }
  for (int v = tid; v < 1280; v += 1024) {
    int p = v / 20, j = v - p * 20;
    nidx[p][j] = idxbuf[(p0 + p) * 20 + j];
  }
  __syncthreads();

  int pp = tid >> 4;                 // point 0..63
  int t15 = tid & 15;
  int off = t15 << 2;                // logical 4-col chunk within 64
  // swizzled write offset (ushorts): chunk (t15>>1)^(pp&7), half t15&1
  int wroff = ((((t15 >> 1) ^ (pp & 7)) << 3) | ((t15 & 1) << 2));

  auto build = [&](int phase, int buf) {
    int kb0 = phase << 2;
    short4 xv[4];
    uint2 hv[4];
    #pragma unroll
    for (int kc = 0; kc < 4; ++kc) {
      int kb = kb0 + kc;
      if (kb >= 61) continue;
      if (kb < 21) {
        int col = (kb == 0) ? (n0 + pp) : nidx[pp][kb - 1];
        xv[kc] = *(const short4*)(xt + ((size_t)col << 6) + off);
      } else {
        int q0 = (kb - 21) * 64 + off;
        hv[kc] = *(const uint2*)(hu + (size_t)(p0 + pp) * 1280 + (q0 >> 1));
      }
    }
    #pragma unroll
    for (int kc = 0; kc < 4; ++kc) {
      int kb = kb0 + kc;
      if (kb >= 61) continue;
      if (kb < 21) {
        *(short4*)&As[buf][kc][pp][wroff] = xv[kc];
      } else {
        int q0 = (kb - 21) * 64 + off;
        uint2 hvv = hv[kc];
        float f0 = bf2f(hvv.x & 0xffffu), f1 = bf2f(hvv.x >> 16);
        float f2 = bf2f(hvv.y & 0xffffu), f3 = bf2f(hvv.y >> 16);
        int ch0 = q0 / 10;
        int rem = q0 - ch0 * 10;      // one magic-div per 4 elements
        float a0 = cfA[ch0], b0 = cfB[ch0];
        float a1 = cfA[ch0 + 1], b1 = cfB[ch0 + 1];
        bool h0 = (rem + 0) >= 10, h1 = (rem + 1) >= 10;
        bool h2 = (rem + 2) >= 10, h3 = (rem + 3) >= 10;
        float v0 = f0 * (h0 ? a1 : a0) + (h0 ? b1 : b0);
        float v1 = f1 * (h1 ? a1 : a0) + (h1 ? b1 : b0);
        float v2 = f2 * (h2 ? a1 : a0) + (h2 ? b1 : b0);
        float v3 = f3 * (h3 ? a1 : a0) + (h3 ? b1 : b0);
        v0 = fmaxf(v0, 0.01f * v0);
        v1 = fmaxf(v1, 0.01f * v1);
        v2 = fmaxf(v2, 0.01f * v2);
        v3 = fmaxf(v3, 0.01f * v3);
        uint2 wv2;
        wv2.x = cvtpk_bf16(v0, v1);
        wv2.y = cvtpk_bf16(v2, v3);
        *(uint2*)&As[buf][kc][pp][wroff] = wv2;
      }
    }
  };

  int lane = tid & 63, wave = tid >> 6;   // wave 0..15
  int m = lane & 15, quad = lane >> 4;
  // swizzled read chunk offsets (ushorts) for ks=0,1 — R8-verified pattern
  int rdoff0 = ((quad ^ (m & 7)) << 3);
  int rdoff1 = (((4 + quad) ^ (m & 7)) << 3);
  f32x4 acc[4] = {};

  build(0, 0);
  __syncthreads();
  for (int phase = 0; phase < 16; ++phase) {
    int buf = phase & 1;
    if (phase < 15) build(phase + 1, buf ^ 1);
    #pragma unroll
    for (int kc = 0; kc < 4; ++kc) {
      int kb = (phase << 2) + kc;
      if (kb >= 61) break;
      #pragma unroll
      for (int ks = 0; ks < 2; ++ks) {
        int rdoff = ks ? rdoff1 : rdoff0;
        short8 afr[4];
        #pragma unroll
        for (int mt = 0; mt < 4; ++mt)
          afr[mt] = *(const short8*)&As[buf][kc][mt * 16 + m][rdoff];
        const ushort* bp = wpack +
            (((size_t)((kb * 2 + ks) * 16 + wave)) << 9) + lane * 8;
        short8 bfr = *(const short8*)bp;
        #pragma unroll
        for (int mt = 0; mt < 4; ++mt)
          acc[mt] = __builtin_amdgcn_mfma_f32_16x16x32_bf16(afr[mt], bfr, acc[mt], 0, 0, 0);
      }
    }
    __syncthreads();
  }
  {
    int col = (wave << 4) + m;          // 0..255
    float sacc = 0.f, ssacc = 0.f;
    #pragma unroll
    for (int mt = 0; mt < 4; ++mt) {
      #pragma unroll
      for (int r = 0; r < 4; ++r) {
        int prow = mt * 16 + quad * 4 + r;
        float v = acc[mt][r];
        sacc += v; ssacc += v * v;
        yraw[(size_t)(p0 + prow) * 256 + col] = v;
      }
    }
    sacc += __shfl_xor(sacc, 16);  sacc += __shfl_xor(sacc, 32);
    ssacc += __shfl_xor(ssacc, 16); ssacc += __shfl_xor(ssacc, 32);
    if (quad == 0) {
      atomicAdd(&stats[col], sacc);
      atomicAdd(&stats[256 + col], ssacc);
    }
  }
}

// ---------------- BN2 + relu + transpose to (b, c, n), v3: float4 stores +
// BN2 coefs computed in-kernel from conv2 stats (kills finalize launch) ----------------
__global__ __launch_bounds__(256) void out_kernel(const float* __restrict__ yraw,
                                                  const float* __restrict__ stats2,
                                                  const float* __restrict__ g2,
                                                  const float* __restrict__ be2,
                                                  float* __restrict__ out) {
  __shared__ float t[64][257];
  __shared__ float c2A[256], c2B[256];
  int tid = threadIdx.x;
  int blk = blockIdx.x;            // 256 = 8 b x 32 n-tiles
  int b = blk >> 5, n0 = (blk & 31) << 6;
  {
    float mm = stats2[tid] * (1.f / 16384.f);
    float var = stats2[256 + tid] * (1.f / 16384.f) - mm * mm;
    float a = g2[tid] * rsqrtf(var + 1e-5f);
    c2A[tid] = a;
    c2B[tid] = be2[tid] - mm * a;
  }
  for (int it = 0; it < 64; ++it)
    t[it][tid] = yraw[(b * 2048 + n0 + it) * 256 + tid];
  __syncthreads();
  int nsub4 = (tid & 15) << 2;
  int cq = tid >> 4;               // 0..15
  for (int it = 0; it < 16; ++it) {
    int c = (it << 4) + cq;
    float a = c2A[c], be = c2B[c];
    float4 v;
    v.x = a * t[nsub4 + 0][c] + be;
    v.y = a * t[nsub4 + 1][c] + be;
    v.z = a * t[nsub4 + 2][c] + be;
    v.w = a * t[nsub4 + 3][c] + be;
    v.x = v.x > 0.f ? v.x : 0.f;
    v.y = v.y > 0.f ? v.y : 0.f;
    v.z = v.z > 0.f ? v.z : 0.f;
    v.w = v.w > 0.f ? v.w : 0.f;
    *(float4*)&out[(size_t)(b * 256 + c) * 2048 + n0 + nsub4] = v;
  }
}

extern "C" void kernel_launch(void* const* d_in, const int* in_sizes, int n_in,
                              void* d_out, int out_size, void* d_ws, size_t ws_size,
                              hipStream_t stream) {
  const float* x   = (const float*)d_in[0];
  const float* w1  = (const float*)d_in[1];
  const float* g1  = (const float*)d_in[3];
  const float* be1 = (const float*)d_in[4];
  const float* w2  = (const float*)d_in[5];
  const float* g2  = (const float*)d_in[7];
  const float* be2 = (const float*)d_in[8];
  float* out = (float*)d_out;
  char* w = (char*)d_ws;
  // workspace layout (~106.6 MB total)
  float* sqf    = (float*)(w);                 // 16384 * 4 (slot 131072 B)
  int*  idxbuf  = (int*)(w + 131072);          // 327680 * 4     = 1310720
  uint* hu      = (uint*)(w + 1441792);        // h bf16: 83886080 B
  float* xtf    = (float*)(w + 1441792);       // fp32 xT, 8 MB — ALIASES hu
  int*  cbuf    = (int*)(w + 9830400);         // 16384*64*4 = 4 MB — ALIASES hu
                                               // (xtf/cbuf dead before conv1)
  float* yraw   = (float*)(w + 85327872);      // 4194304 * 4    = 16777216
  float* stats  = (float*)(w + 102105088);     // 4 * 256 floats
  ushort* wp1   = (ushort*)(w + 102113280);    // 196608 * 2 = 393216
  ushort* wpack = (ushort*)(w + 102506496);    // 999424 * 2 = 1998848
  ushort* xbf_t = (ushort*)(w + 104505344);    // 1048576 * 2 -> end 106602496

  hipMemsetAsync(stats, 0, 4096, stream);
  prep_transpose<<<4928, 256, 0, stream>>>(w1, w2, wp1, wpack,
                                           x, (uint*)xbf_t, xtf, sqf);
  knn_kernel<<<2048, 1024, 0, stream>>>(xbf_t, sqf, cbuf);
  knn_merge<<<4096, 256, 0, stream>>>(xtf, cbuf, idxbuf);
  conv1_mfma<<<1024, 512, 0, stream>>>(xbf_t, idxbuf, wp1, hu, stats);
  conv2_mfma<<<256, 1024, 0, stream>>>(xbf_t, idxbuf, hu, stats, g1, be1,
                                       wpack, yraw, stats + 512);
  out_kernel<<<256, 256, 0, stream>>>(yraw, stats + 512, g2, be2, out);
}

// Round 19
// 284.757 us; speedup vs baseline: 1.0295x; 1.0071x over previous
//
#include <hip/hip_runtime.h>
#include <stdint.h>

typedef unsigned int uint;
typedef unsigned short ushort;
typedef __attribute__((ext_vector_type(8))) short short8;
typedef __attribute__((ext_vector_type(4))) float f32x4;

__device__ __forceinline__ uint f2bf(float f) {
  uint u = __float_as_uint(f);
  return (u + 0x7fffu + ((u >> 16) & 1u)) >> 16;
}
__device__ __forceinline__ float bf2f(uint us) {
  return __uint_as_float(us << 16);
}
__device__ __forceinline__ uint cvtpk_bf16(float lo, float hi) {
  uint r;
  asm("v_cvt_pk_bf16_f32 %0, %1, %2" : "=v"(r) : "v"(lo), "v"(hi));
  return r;
}
__device__ __forceinline__ int lt_count(unsigned long long m) {
  return (int)__builtin_amdgcn_mbcnt_hi((uint)(m >> 32),
             __builtin_amdgcn_mbcnt_lo((uint)m, 0u));
}

// ---------------- fused: weight preprocessing + x transpose ----------------
// blocks 0..255: transpose_x (bf16 xT + fp32 xT + sqnorm).
// blocks 256..4927: prep_weights (wp1 + wpack), g = (blk-256)*256+tid.
__global__ __launch_bounds__(256) void prep_transpose(
    const float* __restrict__ w1, const float* __restrict__ w2,
    ushort* __restrict__ wp1, ushort* __restrict__ wpack,
    const float* __restrict__ x, uint* __restrict__ xtu,
    float* __restrict__ xtf, float* __restrict__ sqf) {
  __shared__ float t[64][65];
  int tid = threadIdx.x;
  if (blockIdx.x >= 256) {
    int g = (blockIdx.x - 256) * 256 + tid;
    if (g < 196608) {
      int chunk = g >> 9;            // (t*2+ks)*16 + ctile
      int r = g & 511;
      int lane = r >> 3, j = r & 7;
      int tks = chunk >> 4;
      int ctile = chunk & 15;
      int tt0 = tks >> 1, ks = tks & 1;
      int c = ctile * 16 + (lane & 15);
      int d = ks * 32 + ((lane >> 4) << 3) + j;
      float val;
      if (tt0 < 11) {
        val = w1[c * 1408 + (64 + d) * 11 + tt0];
      } else {
        float s = 0.f;
        for (int tt = 0; tt < 11; ++tt)
          s += w1[c * 1408 + d * 11 + tt] - w1[c * 1408 + (64 + d) * 11 + tt];
        val = s;
      }
      wp1[g] = (ushort)f2bf(val);
    } else {
      int gp = g - 196608;            // < 999424 = 61*16384
      int chunk = gp >> 9;            // (kb*2+ks)*16 + ctile
      int r = gp & 511;
      int lane = r >> 3, j = r & 7;
      int kb = chunk >> 5;
      int rem = chunk & 31;
      int ks = rem >> 4, ctile = rem & 15;
      int c = ctile * 16 + (lane & 15);
      int k = kb * 64 + ks * 32 + ((lane >> 4) << 3) + j;
      float val;
      if (k < 64) {
        int d = k;
        float s = 0.f;
        for (int jn = 0; jn < 20; ++jn)
          s += w2[c * 5120 + d * 40 + jn] - w2[c * 5120 + (64 + d) * 40 + jn];
        val = s;
      } else if (k < 1344) {
        int q = k - 64; int jn = q >> 6, d = q & 63;
        val = w2[c * 5120 + (64 + d) * 40 + jn];
      } else {
        int q = k - 1344; int ci = q / 20, jj = q - ci * 20;
        val = w2[c * 5120 + ci * 40 + 20 + jj];
      }
      wpack[gp] = (ushort)f2bf(val);
    }
    return;
  }
  // ---- transpose part (manual f2bf kept: feeds kNN ranking) ----
  int blk = blockIdx.x;            // 256 = 8 b x 32 n-tiles
  int b = blk >> 5, n0 = (blk & 31) << 6;
  const float* xb = x + b * 131072;
  #pragma unroll
  for (int it = 0; it < 16; ++it) {
    int d = (it << 2) + (tid >> 6);
    int n = tid & 63;
    t[d][n] = xb[d * 2048 + n0 + n];
  }
  __syncthreads();
  #pragma unroll
  for (int it = 0; it < 8; ++it) {
    int n = (it << 3) + (tid >> 5);
    int dp = tid & 31;
    float f0 = t[2 * dp][n], f1 = t[2 * dp + 1][n];
    uint v = f2bf(f0) | (f2bf(f1) << 16);
    size_t col = (size_t)(b * 2048 + n0 + n);
    xtu[col * 32 + dp] = v;
    float2 fv; fv.x = f0; fv.y = f1;
    *(float2*)&xtf[(col << 6) + 2 * dp] = fv;
    float s = f0 * f0 + f1 * f1;
    #pragma unroll
    for (int off = 16; off > 0; off >>= 1) s += __shfl_xor(s, off);
    if (dp == 0) sqf[col] = s;
  }
}

// ---------------- kNN v10: threshold + compact + rank; dist rows padded to
// 1040 (stride % 32 banks = 16) so the 4 quads' writes are 2-way not 4-way
// (2-way is free per m136). 75 KB LDS -> still 2 blocks/CU. ----------------
__global__ __launch_bounds__(1024) void knn_kernel(
    const ushort* __restrict__ xbf_t, const float* __restrict__ sqf,
    int* __restrict__ cbuf) {
  __shared__ uint dist[16][1040];   // 66560 B (padded rows)
  __shared__ uint surv[16][132];    // 8448 B (128 max survivors + pad)
  int tid = threadIdx.x;
  int wv = tid >> 6, lane = tid & 63;
  int grp = blockIdx.x >> 1;
  int half = blockIdx.x & 1;
  int cbase = half << 10;
  int row0 = grp << 4;
  int b = row0 >> 11, n0 = row0 & 2047;
  const ushort* xt = xbf_t + ((size_t)b << 17);
  const float* sqb = sqf + (b << 11);
  int m = lane & 15, quad = lane >> 4;
  short8 afr0 = *(const short8*)(xt + ((size_t)(n0 + m) << 6) + quad * 8);
  short8 afr1 = *(const short8*)(xt + ((size_t)(n0 + m) << 6) + 32 + quad * 8);
  for (int t = 0; t < 4; ++t) {
    int lcol = (((wv << 2) + t) << 4) + m;
    int col = cbase + lcol;
    short8 bfr0 = *(const short8*)(xt + ((size_t)col << 6) + quad * 8);
    short8 bfr1 = *(const short8*)(xt + ((size_t)col << 6) + 32 + quad * 8);
    f32x4 c = {};
    c = __builtin_amdgcn_mfma_f32_16x16x32_bf16(afr0, bfr0, c, 0, 0, 0);
    c = __builtin_amdgcn_mfma_f32_16x16x32_bf16(afr1, bfr1, c, 0, 0, 0);
    float sq = sqb[col];
    #pragma unroll
    for (int r = 0; r < 4; ++r) {
      float f = sq - 2.f * c[r];
      uint u = __float_as_uint(f);
      uint srt = u ^ ((uint)((int)u >> 31) | 0x80000000u);
      dist[quad * 4 + r][lcol] = (srt & 0xFFFFF800u) | (uint)col;
    }
  }
  __syncthreads();
  uint* dr = dist[wv];
  int selfl = (n0 + wv) - cbase;
  if (selfl >= 0 && selfl < 1024 && ((selfl & 63) == lane))
    dr[selfl] = 0xFFFFFFFFu;

  // phase 1: load this lane's 16 keys to registers, track lane min
  uint key[16];
  uint v0 = 0xFFFFFFFFu;
  #pragma unroll
  for (int l = 0; l < 16; ++l) {
    uint v = dr[(l << 6) + lane];
    key[l] = v;
    v0 = v0 < v ? v0 : v;
  }

  // phase 2: bitonic sort of the 64 lane-minima across lanes; T = element 31
  uint s = v0;
  #pragma unroll
  for (int k = 2; k <= 64; k <<= 1) {
    #pragma unroll
    for (int j = k >> 1; j > 0; j >>= 1) {
      uint o = (uint)__shfl_xor((int)s, j);
      bool up = ((lane & k) == 0);
      bool lower = ((lane & j) == 0);
      uint mn = s < o ? s : o;
      uint mx = s < o ? o : s;
      s = (lower == up) ? mn : mx;
    }
  }
  uint T = (uint)__shfl((int)s, 31);

  // phase 3: ballot-compact survivors (key <= T) into surv[wv]
  int base = 0;
  #pragma unroll
  for (int l = 0; l < 16; ++l) {
    uint v = key[l];
    bool f = (v <= T);
    unsigned long long mk = __ballot(f);
    if (f) {
      int pos = base + lt_count(mk);
      if (pos < 128) surv[wv][pos] = v;
    }
    base += __popcll(mk);
  }
  int S = base < 128 ? base : 128;
  if (lane < 4) surv[wv][S + lane] = 0xFFFFFFFFu;   // pad for b128 tail read

  // phase 4: exact rank of each survivor = count of strictly-smaller survivors
  int outb = (row0 + wv) * 64 + (half << 5);
  uint k0 = (lane < S) ? surv[wv][lane] : 0xFFFFFFFFu;
  int r0 = 0;
  if (S > 64) {
    uint k1 = (lane + 64 < S) ? surv[wv][lane + 64] : 0xFFFFFFFFu;
    int r1 = 0;
    for (int i = 0; i < S; i += 4) {
      uint4 q = *(const uint4*)&surv[wv][i];   // broadcast read
      r0 += (q.x < k0) + (q.y < k0) + (q.z < k0) + (q.w < k0);
      r1 += (q.x < k1) + (q.y < k1) + (q.z < k1) + (q.w < k1);
    }
    if (lane + 64 < S && r1 < 32) cbuf[outb + r1] = (int)(k1 & 2047u);
  } else {
    for (int i = 0; i < S; i += 4) {
      uint4 q = *(const uint4*)&surv[wv][i];   // broadcast read
      r0 += (q.x < k0) + (q.y < k0) + (q.z < k0) + (q.w < k0);
    }
  }
  if (lane < S && r0 < 32) cbuf[outb + r0] = (int)(k0 & 2047u);
}

// ---------------- kNN merge: fp64 exact re-rank of 64 candidates/row ----------------
__global__ __launch_bounds__(256) void knn_merge(
    const float* __restrict__ xtf, const int* __restrict__ cbuf,
    int* __restrict__ idxout) {
  __shared__ double dkey[4][64];
  __shared__ int ccol[4][64];
  int tid = threadIdx.x;
  int wv = tid >> 6, lane = tid & 63;
  int row = (blockIdx.x << 2) + wv;
  int b = row >> 11, n = row & 2047;
  int ci = cbuf[row * 64 + lane];
  const float* xc = xtf + ((size_t)b << 17);
  const float4* xj4 = (const float4*)(xc + ((size_t)ci << 6));
  const float4* xi4 = (const float4*)(xc + ((size_t)n << 6));
  double dt = 0.0, s2 = 0.0;
  #pragma unroll 4
  for (int d4 = 0; d4 < 16; ++d4) {
    float4 vj = xj4[d4];
    float4 vi = xi4[d4];
    double a0 = (double)vj.x, a1 = (double)vj.y, a2 = (double)vj.z, a3 = (double)vj.w;
    s2 += a0 * a0 + a1 * a1 + a2 * a2 + a3 * a3;
    dt += (double)vi.x * a0 + (double)vi.y * a1 + (double)vi.z * a2 + (double)vi.w * a3;
  }
  dkey[wv][lane] = s2 - 2.0 * dt;
  ccol[wv][lane] = ci;
  __syncthreads();
  double kl = dkey[wv][lane];
  int rank = 0;
  for (int mm = 0; mm < 64; ++mm) {
    double km = dkey[wv][mm];
    int cm = ccol[wv][mm];
    if (km < kl || (km == kl && cm < ci)) ++rank;
  }
  if (rank < 20) idxout[row * 20 + rank] = ci;
}

// ---------------- conv1 as bf16 MFMA v5 + cvt_pk epilogue:
// 8-wave blocks (2 ctile passes/wave), chunk-major XOR-swizzled LDS.
// (v6 tap-split REVERTED: 6-waves/SIMD cap spilled acc — reg floor ~90.)
// Block: 16 points x 256 channels (8 waves; pass p: ctile = p*8+wave).
// LDS sl[s][chunk][p^chunk][8]: chunk = ks*4+quad (conflict-free, R6). ----------------
__global__ __launch_bounds__(512, 4) void conv1_mfma(
    const ushort* __restrict__ xbf_t, const int* __restrict__ idxbuf,
    const ushort* __restrict__ wp1, uint* __restrict__ hu,
    float* __restrict__ stats) {
  __shared__ ushort sl[21][8][16][8];   // 43008 B
  __shared__ int nidx[16][20];
  int tid = threadIdx.x;
  int p0 = blockIdx.x << 4;
  int b = p0 >> 11, n0 = p0 & 2047;
  const ushort* xt = xbf_t + ((size_t)b << 17);
  for (int v = tid; v < 320; v += 512) {
    int p = v / 20, j = v - p * 20;
    nidx[p][j] = idxbuf[(p0 + p) * 20 + j];
  }
  __syncthreads();
  for (int v = tid; v < 2688; v += 512) {
    int s = v >> 7;
    int r = v & 127;
    int p = r >> 3, i = r & 7;
    int col = (s == 0) ? (n0 + p) : nidx[p][s - 1];
    *(short8*)&sl[s][i][p ^ i][0] =
        *(const short8*)(xt + ((size_t)col << 6) + (i << 3));
  }
  __syncthreads();
  int lane = tid & 63, wave = tid >> 6;   // wave 0..7
  int m = lane & 15, quad = lane >> 4;
  #pragma unroll 1
  for (int pass = 0; pass < 2; ++pass) {
    int ctile = (pass << 3) + wave;
    int c = ctile * 16 + m;
    f32x4 acc[10] = {};
    f32x4 cacc = {};
    // ks-split: only 12 B-fragments (tb[11]+ub, 48 VGPRs) live at a time
    #pragma unroll 1
    for (int ks = 0; ks < 2; ++ks) {
      int cch = ks * 4 + quad;          // LDS chunk for this lane
      int ms = m ^ cch;                 // XOR-swizzled point slot
      short8 tb[11];
      #pragma unroll
      for (int t = 0; t < 11; ++t)
        tb[t] = *(const short8*)(wp1 + (((t * 2 + ks) * 16 + ctile) << 9) + lane * 8);
      short8 ub = *(const short8*)(wp1 + (((22 + ks) * 16 + ctile) << 9) + lane * 8);
      {
        short8 a = *(const short8*)&sl[0][cch][ms][0];
        cacc = __builtin_amdgcn_mfma_f32_16x16x32_bf16(a, ub, cacc, 0, 0, 0);
      }
      // slice-outer: read each slice once, accumulate into all valid ko = s-1-t
      #pragma unroll
      for (int s = 1; s <= 20; ++s) {
        short8 a = *(const short8*)&sl[s][cch][ms][0];
        #pragma unroll
        for (int t = 0; t < 11; ++t) {
          int ko = s - 1 - t;
          if (ko >= 0 && ko < 10)
            acc[ko] = __builtin_amdgcn_mfma_f32_16x16x32_bf16(a, tb[t], acc[ko], 0, 0, 0);
        }
      }
    }
    // epilogue: D col=lane&15 -> channel, row=quad*4+r -> point; fused stats
    float sacc = 0.f, ssacc = 0.f;
    #pragma unroll
    for (int r = 0; r < 4; ++r) {
      int p = (quad << 2) + r;
      int base5 = ((p0 + p) * 256 + c) * 5;
      float cc = cacc[r];
      #pragma unroll
      for (int q = 0; q < 5; ++q) {
        float f0 = acc[2 * q][r] + cc;
        float f1 = acc[2 * q + 1][r] + cc;
        sacc += f0 + f1;
        ssacc += f0 * f0 + f1 * f1;
        hu[base5 + q] = cvtpk_bf16(f0, f1);   // RNE pack, 1 instr vs ~7
      }
    }
    sacc += __shfl_xor(sacc, 16);  sacc += __shfl_xor(sacc, 32);
    ssacc += __shfl_xor(ssacc, 16); ssacc += __shfl_xor(ssacc, 32);
    if (quad == 0) {
      atomicAdd(&stats[c], sacc);
      atomicAdd(&stats[256 + c], ssacc);
    }
  }
}

// ---------------- conv2 as bf16 MFMA GEMM v12: M=64 x N=256 single block
// (grid 256, 1024 thr / 16 waves) — dequant runs ONCE per h element (was 2x
// under the N-half split; dequant was the 47%-VALUBusy hotspot). B-traffic
// unchanged at 0.5 GB; occupancy cap unchanged (16 waves/CU). BN1 coefs
// in-kernel. R8-verified conflict-free 4-col write swizzle
// (((t15>>1)^(pp&7))<<3 | (t15&1)<<2); read swizzle unchanged. ----------------
__global__ __launch_bounds__(1024, 4) void conv2_mfma(
    const ushort* __restrict__ xbf_t, const int* __restrict__ idxbuf,
    const uint* __restrict__ hu, const float* __restrict__ stats1,
    const float* __restrict__ g1, const float* __restrict__ be1,
    const ushort* __restrict__ wpack, float* __restrict__ yraw,
    float* __restrict__ stats) {
  __shared__ ushort As[2][4][64][64];   // 65536 B (swizzled)
  __shared__ int nidx[64][20];          // 5120 B
  __shared__ float cfA[257], cfB[257];  // 2056 B -> total 72712 B
  int tid = threadIdx.x;
  int p0 = blockIdx.x << 6;             // 64 points per block, grid 256
  int b = p0 >> 11, n0 = p0 & 2047;
  const ushort* xt = xbf_t + ((size_t)b << 17);

  if (tid < 256) {
    float mm = stats1[tid] * (1.f / 163840.f);
    float var = stats1[256 + tid] * (1.f / 163840.f) - mm * mm;
    float a = g1[tid] * rsqrtf(var + 1e-5f);
    cfA[tid] = a;
    cfB[tid] = be1[tid] - mm * a;
    if (tid == 0) { cfA[256] = 0.f; cfB[256] = 0.f; }
  }
  for (int v = tid; v < 1280; v += 1024) {
    int p = v / 20, j = v - p * 20;
    nidx[p][j] = idxbuf[(p0 + p) * 20 + j];
  }
  __syncthreads();

  int pp = tid >> 4;                 // point 0..63
  int t15 = tid & 15;
  int off = t15 << 2;                // logical 4-col chunk within 64
  // swizzled write offset (ushorts): chunk (t15>>1)^(pp&7), half t15&1
  int wroff = ((((t15 >> 1) ^ (pp & 7)) << 3) | ((t15 & 1) << 2));

  auto build = [&](int phase, int buf) {
    int kb0 = phase << 2;
    short4 xv[4];
    uint2 hv[4];
    #pragma unroll
    for (int kc = 0; kc < 4; ++kc) {
      int kb = kb0 + kc;
      if (kb >= 61) continue;
      if (kb < 21) {
        int col = (kb == 0) ? (n0 + pp) : nidx[pp][kb - 1];
        xv[kc] = *(const short4*)(xt + ((size_t)col << 6) + off);
      } else {
        int q0 = (kb - 21) * 64 + off;
        hv[kc] = *(const uint2*)(hu + (size_t)(p0 + pp) * 1280 + (q0 >> 1));
      }
    }
    #pragma unroll
    for (int kc = 0; kc < 4; ++kc) {
      int kb = kb0 + kc;
      if (kb >= 61) continue;
      if (kb < 21) {
        *(short4*)&As[buf][kc][pp][wroff] = xv[kc];
      } else {
        int q0 = (kb - 21) * 64 + off;
        uint2 hvv = hv[kc];
        float f0 = bf2f(hvv.x & 0xffffu), f1 = bf2f(hvv.x >> 16);
        float f2 = bf2f(hvv.y & 0xffffu), f3 = bf2f(hvv.y >> 16);
        int ch0 = q0 / 10;
        int rem = q0 - ch0 * 10;      // one magic-div per 4 elements
        float a0 = cfA[ch0], b0 = cfB[ch0];
        float a1 = cfA[ch0 + 1], b1 = cfB[ch0 + 1];
        bool h0 = (rem + 0) >= 10, h1 = (rem + 1) >= 10;
        bool h2 = (rem + 2) >= 10, h3 = (rem + 3) >= 10;
        float v0 = f0 * (h0 ? a1 : a0) + (h0 ? b1 : b0);
        float v1 = f1 * (h1 ? a1 : a0) + (h1 ? b1 : b0);
        float v2 = f2 * (h2 ? a1 : a0) + (h2 ? b1 : b0);
        float v3 = f3 * (h3 ? a1 : a0) + (h3 ? b1 : b0);
        v0 = fmaxf(v0, 0.01f * v0);
        v1 = fmaxf(v1, 0.01f * v1);
        v2 = fmaxf(v2, 0.01f * v2);
        v3 = fmaxf(v3, 0.01f * v3);
        uint2 wv2;
        wv2.x = cvtpk_bf16(v0, v1);
        wv2.y = cvtpk_bf16(v2, v3);
        *(uint2*)&As[buf][kc][pp][wroff] = wv2;
      }
    }
  };

  int lane = tid & 63, wave = tid >> 6;   // wave 0..15
  int m = lane & 15, quad = lane >> 4;
  // swizzled read chunk offsets (ushorts) for ks=0,1 — R8-verified pattern
  int rdoff0 = ((quad ^ (m & 7)) << 3);
  int rdoff1 = (((4 + quad) ^ (m & 7)) << 3);
  f32x4 acc[4] = {};

  build(0, 0);
  __syncthreads();
  for (int phase = 0; phase < 16; ++phase) {
    int buf = phase & 1;
    if (phase < 15) build(phase + 1, buf ^ 1);
    #pragma unroll
    for (int kc = 0; kc < 4; ++kc) {
      int kb = (phase << 2) + kc;
      if (kb >= 61) break;
      #pragma unroll
      for (int ks = 0; ks < 2; ++ks) {
        int rdoff = ks ? rdoff1 : rdoff0;
        short8 afr[4];
        #pragma unroll
        for (int mt = 0; mt < 4; ++mt)
          afr[mt] = *(const short8*)&As[buf][kc][mt * 16 + m][rdoff];
        const ushort* bp = wpack +
            (((size_t)((kb * 2 + ks) * 16 + wave)) << 9) + lane * 8;
        short8 bfr = *(const short8*)bp;
        #pragma unroll
        for (int mt = 0; mt < 4; ++mt)
          acc[mt] = __builtin_amdgcn_mfma_f32_16x16x32_bf16(afr[mt], bfr, acc[mt], 0, 0, 0);
      }
    }
    __syncthreads();
  }
  {
    int col = (wave << 4) + m;          // 0..255
    float sacc = 0.f, ssacc = 0.f;
    #pragma unroll
    for (int mt = 0; mt < 4; ++mt) {
      #pragma unroll
      for (int r = 0; r < 4; ++r) {
        int prow = mt * 16 + quad * 4 + r;
        float v = acc[mt][r];
        sacc += v; ssacc += v * v;
        yraw[(size_t)(p0 + prow) * 256 + col] = v;
      }
    }
    sacc += __shfl_xor(sacc, 16);  sacc += __shfl_xor(sacc, 32);
    ssacc += __shfl_xor(ssacc, 16); ssacc += __shfl_xor(ssacc, 32);
    if (quad == 0) {
      atomicAdd(&stats[col], sacc);
      atomicAdd(&stats[256 + col], ssacc);
    }
  }
}

// ---------------- BN2 + relu + transpose to (b, c, n), v3: float4 stores +
// BN2 coefs computed in-kernel from conv2 stats (kills finalize launch) ----------------
__global__ __launch_bounds__(256) void out_kernel(const float* __restrict__ yraw,
                                                  const float* __restrict__ stats2,
                                                  const float* __restrict__ g2,
                                                  const float* __restrict__ be2,
                                                  float* __restrict__ out) {
  __shared__ float t[64][257];
  __shared__ float c2A[256], c2B[256];
  int tid = threadIdx.x;
  int blk = blockIdx.x;            // 256 = 8 b x 32 n-tiles
  int b = blk >> 5, n0 = (blk & 31) << 6;
  {
    float mm = stats2[tid] * (1.f / 16384.f);
    float var = stats2[256 + tid] * (1.f / 16384.f) - mm * mm;
    float a = g2[tid] * rsqrtf(var + 1e-5f);
    c2A[tid] = a;
    c2B[tid] = be2[tid] - mm * a;
  }
  for (int it = 0; it < 64; ++it)
    t[it][tid] = yraw[(b * 2048 + n0 + it) * 256 + tid];
  __syncthreads();
  int nsub4 = (tid & 15) << 2;
  int cq = tid >> 4;               // 0..15
  for (int it = 0; it < 16; ++it) {
    int c = (it << 4) + cq;
    float a = c2A[c], be = c2B[c];
    float4 v;
    v.x = a * t[nsub4 + 0][c] + be;
    v.y = a * t[nsub4 + 1][c] + be;
    v.z = a * t[nsub4 + 2][c] + be;
    v.w = a * t[nsub4 + 3][c] + be;
    v.x = v.x > 0.f ? v.x : 0.f;
    v.y = v.y > 0.f ? v.y : 0.f;
    v.z = v.z > 0.f ? v.z : 0.f;
    v.w = v.w > 0.f ? v.w : 0.f;
    *(float4*)&out[(size_t)(b * 256 + c) * 2048 + n0 + nsub4] = v;
  }
}

extern "C" void kernel_launch(void* const* d_in, const int* in_sizes, int n_in,
                              void* d_out, int out_size, void* d_ws, size_t ws_size,
                              hipStream_t stream) {
  const float* x   = (const float*)d_in[0];
  const float* w1  = (const float*)d_in[1];
  const float* g1  = (const float*)d_in[3];
  const float* be1 = (const float*)d_in[4];
  const float* w2  = (const float*)d_in[5];
  const float* g2  = (const float*)d_in[7];
  const float* be2 = (const float*)d_in[8];
  float* out = (float*)d_out;
  char* w = (char*)d_ws;
  // workspace layout (~106.6 MB total)
  float* sqf    = (float*)(w);                 // 16384 * 4 (slot 131072 B)
  int*  idxbuf  = (int*)(w + 131072);          // 327680 * 4     = 1310720
  uint* hu      = (uint*)(w + 1441792);        // h bf16: 83886080 B
  float* xtf    = (float*)(w + 1441792);       // fp32 xT, 8 MB — ALIASES hu
  int*  cbuf    = (int*)(w + 9830400);         // 16384*64*4 = 4 MB — ALIASES hu
                                               // (xtf/cbuf dead before conv1)
  float* yraw   = (float*)(w + 85327872);      // 4194304 * 4    = 16777216
  float* stats  = (float*)(w + 102105088);     // 4 * 256 floats
  ushort* wp1   = (ushort*)(w + 102113280);    // 196608 * 2 = 393216
  ushort* wpack = (ushort*)(w + 102506496);    // 999424 * 2 = 1998848
  ushort* xbf_t = (ushort*)(w + 104505344);    // 1048576 * 2 -> end 106602496

  hipMemsetAsync(stats, 0, 4096, stream);
  prep_transpose<<<4928, 256, 0, stream>>>(w1, w2, wp1, wpack,
                                           x, (uint*)xbf_t, xtf, sqf);
  knn_kernel<<<2048, 1024, 0, stream>>>(xbf_t, sqf, cbuf);
  knn_merge<<<4096, 256, 0, stream>>>(xtf, cbuf, idxbuf);
  conv1_mfma<<<1024, 512, 0, stream>>>(xbf_t, idxbuf, wp1, hu, stats);
  conv2_mfma<<<256, 1024, 0, stream>>>(xbf_t, idxbuf, hu, stats, g1, be1,
                                       wpack, yraw, stats + 512);
  out_kernel<<<256, 256, 0, stream>>>(yraw, stats + 512, g2, be2, out);
}